// Round 1
// baseline (8147.752 us; speedup 1.0000x reference)
//
#include <hip/hip_runtime.h>

// Problem constants (from reference)
#define MULT 64
#define FEATD 256
#define ZDIM 10

__device__ __forceinline__ float4 fma4(float a, float4 b, float4 c) {
    return make_float4(fmaf(a, b.x, c.x), fmaf(a, b.y, c.y),
                       fmaf(a, b.z, c.z), fmaf(a, b.w, c.w));
}

#define INV640f 0.03952847075210474f   // 1/sqrt(640)
#define ISQ2f   0.7071067811865476f    // 1/sqrt(2)
#define ISQ3f   0.5773502691896258f    // 1/sqrt(3)

// ---------------------------------------------------------------------------
// K0: transform x (n,256 natural: [x0(64) | x1(64,3)]) -> xr (n,u,4) layout:
//     xr[n*256 + u*4 + 0] = x[n,u]            (x0)
//     xr[n*256 + u*4 + 1+k] = x[n, 64+3u+k]   (x1[u,k])
// ---------------------------------------------------------------------------
__global__ __launch_bounds__(256) void transform_x(
    const float* __restrict__ x, float* __restrict__ xr, int N)
{
    int idx = blockIdx.x * 256 + threadIdx.x;     // over N*64 (n,u) pairs
    if (idx >= N * MULT) return;
    int n = idx >> 6;
    int u = idx & 63;
    const float* row = x + (size_t)n * FEATD;
    float a = row[u];
    const float* x1p = row + MULT + u * 3;
    ((float4*)xr)[idx] = make_float4(a, x1p[0], x1p[1], x1p[2]);
}

// ---------------------------------------------------------------------------
// fctp inner loop: thread = one node, computes 16 w-outputs (o0 + o1[3]) for
// w in [wb, wb+16). Y-GEMM form: o[w] = sum_u sum_v (x*z) * W[u,v,w].
// W indices are uniform across the wave -> scalar/broadcast loads.
// ---------------------------------------------------------------------------
__device__ __forceinline__ void fctp_accum(
    const float4* __restrict__ xv4, const float* __restrict__ zr,
    const float* __restrict__ W0, const float* __restrict__ W1, int wb,
    float (&acc0)[16], float (&acc1)[16][3])
{
#pragma unroll
    for (int wi = 0; wi < 16; ++wi) {
        acc0[wi] = 0.f; acc1[wi][0] = 0.f; acc1[wi][1] = 0.f; acc1[wi][2] = 0.f;
    }
    for (int u = 0; u < MULT; ++u) {
        float4 xv = xv4[u];
#pragma unroll
        for (int v = 0; v < ZDIM; ++v) {
            float zv = zr[v];
            float b0 = xv.x * zv, b1 = xv.y * zv, b2 = xv.z * zv, b3 = xv.w * zv;
            const float* W0p = W0 + (u * ZDIM + v) * MULT + wb;
            const float* W1p = W1 + (u * ZDIM + v) * MULT + wb;
#pragma unroll
            for (int wi = 0; wi < 16; ++wi) {
                float w0v = W0p[wi];
                float w1v = W1p[wi];
                acc0[wi]    = fmaf(b0, w0v, acc0[wi]);
                acc1[wi][0] = fmaf(b1, w1v, acc1[wi][0]);
                acc1[wi][1] = fmaf(b2, w1v, acc1[wi][1]);
                acc1[wi][2] = fmaf(b3, w1v, acc1[wi][2]);
            }
        }
    }
}

// ---------------------------------------------------------------------------
// K1: stage A — s = fctp(x,z,W_si) (natural layout), xl = fctp(x,z,W_l1)
//     (xr layout, consumed by edge gather). grid = (ceil(N/256), 4 w-chunks)
// ---------------------------------------------------------------------------
__global__ __launch_bounds__(256) void fctp_stageA(
    const float* __restrict__ xr, const float* __restrict__ z,
    const float* __restrict__ Wsi0, const float* __restrict__ Wsi1,
    const float* __restrict__ Wl10, const float* __restrict__ Wl11,
    float* __restrict__ s_out, float* __restrict__ xlr, int N)
{
    int n = blockIdx.x * 256 + threadIdx.x;
    if (n >= N) return;
    int wb = blockIdx.y * 16;

    float zr[ZDIM];
#pragma unroll
    for (int v = 0; v < ZDIM; ++v) zr[v] = z[n * ZDIM + v] * INV640f;

    const float4* xv4 = (const float4*)xr + (size_t)n * MULT;
    float acc0[16], acc1[16][3];

    // ---- fctp #1: s (natural layout) ----
    fctp_accum(xv4, zr, Wsi0, Wsi1, wb, acc0, acc1);
    {
        float* sp = s_out + (size_t)n * FEATD;
        float4* sp0 = (float4*)(sp + wb);
#pragma unroll
        for (int q = 0; q < 4; ++q)
            sp0[q] = make_float4(acc0[4*q], acc0[4*q+1], acc0[4*q+2], acc0[4*q+3]);
        float a1[48];
#pragma unroll
        for (int wi = 0; wi < 16; ++wi) {
            a1[3*wi] = acc1[wi][0]; a1[3*wi+1] = acc1[wi][1]; a1[3*wi+2] = acc1[wi][2];
        }
        float4* sp1 = (float4*)(sp + MULT + 3 * wb);
#pragma unroll
        for (int q = 0; q < 12; ++q)
            sp1[q] = make_float4(a1[4*q], a1[4*q+1], a1[4*q+2], a1[4*q+3]);
    }

    // ---- fctp #2: xl (xr layout) ----
    fctp_accum(xv4, zr, Wl10, Wl11, wb, acc0, acc1);
    {
        float4* xp = (float4*)xlr + (size_t)n * MULT + wb;
#pragma unroll
        for (int wi = 0; wi < 16; ++wi)
            xp[wi] = make_float4(acc0[wi], acc1[wi][0], acc1[wi][1], acc1[wi][2]);
    }
}

// ---------------------------------------------------------------------------
// K2: edge stage. Block = 256 threads = 64 edges.
//  stage 1: w_tile[64][256] = elem_tile(64x32) @ tp_weight(32x256) into LDS
//           (wave g handles edges g*16..g*16+15; lane l handles cols 4l..4l+3)
//  stage 2: thread (e_l = t>>2, p = t&3) handles u in [16p,16p+16):
//           gather xl[src], TP with sh/w, atomicAdd float4-group into agg[dst]
// ---------------------------------------------------------------------------
#define WT_IDX(r, c) (((r) << 8) + ((((c) + ((r) << 2))) & 255))

__global__ __launch_bounds__(256) void edge_kernel(
    const int* __restrict__ esrc, const int* __restrict__ edst,
    const float* __restrict__ elem, const float* __restrict__ eattr,
    const float* __restrict__ tpw, const float* __restrict__ xlr,
    float* __restrict__ aggr, int E)
{
    __shared__ __align__(16) float wt[64 * 256];
    int t = threadIdx.x;
    int eb = blockIdx.x * 64;

    // ---- stage 1: w-tile GEMM ----
    {
        int g = __builtin_amdgcn_readfirstlane(t >> 6);  // wave id, uniform
        int l = t & 63;
        float4 acc[16];
#pragma unroll
        for (int j = 0; j < 16; ++j) acc[j] = make_float4(0.f, 0.f, 0.f, 0.f);
        const float4* tpw4 = (const float4*)tpw;         // [32][64] of float4

        for (int vb = 0; vb < 8; ++vb) {
            float4 tp0 = tpw4[(vb*4 + 0) * 64 + l];
            float4 tp1 = tpw4[(vb*4 + 1) * 64 + l];
            float4 tp2 = tpw4[(vb*4 + 2) * 64 + l];
            float4 tp3 = tpw4[(vb*4 + 3) * 64 + l];
#pragma unroll
            for (int j = 0; j < 16; ++j) {
                int e = eb + g * 16 + j;
                if (e > E - 1) e = E - 1;                // uniform clamp (safe OOB)
                float4 em = *(const float4*)(elem + (size_t)e * 32 + vb * 4);
                acc[j] = fma4(em.x, tp0, acc[j]);
                acc[j] = fma4(em.y, tp1, acc[j]);
                acc[j] = fma4(em.z, tp2, acc[j]);
                acc[j] = fma4(em.w, tp3, acc[j]);
            }
        }
#pragma unroll
        for (int j = 0; j < 16; ++j)
            *(float4*)&wt[WT_IDX(g * 16 + j, l * 4)] = acc[j];
    }
    __syncthreads();

    // ---- stage 2: per-edge tensor product + scatter ----
    int e_l = t >> 2, p = t & 3;
    int e = eb + e_l;
    if (e < E) {
        int src = esrc[e], dst = edst[e];
        float4 at = *(const float4*)(eattr + (size_t)e * 4);
        float sh0s = at.x * ISQ2f;
        float s1xs = at.y * ISQ2f, s1ys = at.z * ISQ2f, s1zs = at.w * ISQ2f;
        const float c43 = ISQ2f * ISQ3f;

        float w1s[16], w2s[16], w3s[16], w4s[16];
#pragma unroll
        for (int q = 0; q < 4; ++q) {
            float4 a = *(const float4*)&wt[WT_IDX(e_l,       p*16 + q*4)];
            float4 b = *(const float4*)&wt[WT_IDX(e_l,  64 + p*16 + q*4)];
            float4 c = *(const float4*)&wt[WT_IDX(e_l, 128 + p*16 + q*4)];
            float4 d = *(const float4*)&wt[WT_IDX(e_l, 192 + p*16 + q*4)];
            w1s[q*4] = a.x; w1s[q*4+1] = a.y; w1s[q*4+2] = a.z; w1s[q*4+3] = a.w;
            w2s[q*4] = b.x; w2s[q*4+1] = b.y; w2s[q*4+2] = b.z; w2s[q*4+3] = b.w;
            w3s[q*4] = c.x; w3s[q*4+1] = c.y; w3s[q*4+2] = c.z; w3s[q*4+3] = c.w;
            w4s[q*4] = d.x; w4s[q*4+1] = d.y; w4s[q*4+2] = d.z; w4s[q*4+3] = d.w;
        }

        const float4* xs = (const float4*)xlr + (size_t)src * MULT + p * 16;
        float* ad = aggr + (size_t)dst * FEATD + p * 64;
#pragma unroll
        for (int i = 0; i < 16; ++i) {
            float4 xv = xs[i];
            float dot3 = xv.y * at.y + xv.z * at.z + xv.w * at.w;
            float e0  = fmaf(w1s[i] * xv.x, sh0s, c43 * w4s[i] * dot3);
            float e1x = fmaf(w2s[i] * xv.x, s1xs, w3s[i] * xv.y * sh0s);
            float e1y = fmaf(w2s[i] * xv.x, s1ys, w3s[i] * xv.z * sh0s);
            float e1z = fmaf(w2s[i] * xv.x, s1zs, w3s[i] * xv.w * sh0s);
            atomicAdd(ad + i*4 + 0, e0);
            atomicAdd(ad + i*4 + 1, e1x);
            atomicAdd(ad + i*4 + 2, e1y);
            atomicAdd(ad + i*4 + 3, e1z);
        }
    }
}

// ---------------------------------------------------------------------------
// K3: stage C — out = s + fctp(agg,z,W_l2)/10  (0.1*INV640 folded into z)
// ---------------------------------------------------------------------------
__global__ __launch_bounds__(256) void fctp_stageC(
    const float* __restrict__ aggr, const float* __restrict__ z,
    const float* __restrict__ W0, const float* __restrict__ W1,
    const float* __restrict__ s_in, float* __restrict__ out, int N)
{
    int n = blockIdx.x * 256 + threadIdx.x;
    if (n >= N) return;
    int wb = blockIdx.y * 16;

    float zr[ZDIM];
#pragma unroll
    for (int v = 0; v < ZDIM; ++v) zr[v] = z[n * ZDIM + v] * (INV640f * 0.1f);

    const float4* xv4 = (const float4*)aggr + (size_t)n * MULT;
    float acc0[16], acc1[16][3];
    fctp_accum(xv4, zr, W0, W1, wb, acc0, acc1);

    const float* sp = s_in + (size_t)n * FEATD;
    float* op = out + (size_t)n * FEATD;

    const float4* s0 = (const float4*)(sp + wb);
    float4* o0 = (float4*)(op + wb);
#pragma unroll
    for (int q = 0; q < 4; ++q) {
        float4 sv = s0[q];
        o0[q] = make_float4(sv.x + acc0[4*q],   sv.y + acc0[4*q+1],
                            sv.z + acc0[4*q+2], sv.w + acc0[4*q+3]);
    }
    float a1[48];
#pragma unroll
    for (int wi = 0; wi < 16; ++wi) {
        a1[3*wi] = acc1[wi][0]; a1[3*wi+1] = acc1[wi][1]; a1[3*wi+2] = acc1[wi][2];
    }
    const float4* s1 = (const float4*)(sp + MULT + 3 * wb);
    float4* o1 = (float4*)(op + MULT + 3 * wb);
#pragma unroll
    for (int q = 0; q < 12; ++q) {
        float4 sv = s1[q];
        o1[q] = make_float4(sv.x + a1[4*q],   sv.y + a1[4*q+1],
                            sv.z + a1[4*q+2], sv.w + a1[4*q+3]);
    }
}

// ---------------------------------------------------------------------------
extern "C" void kernel_launch(void* const* d_in, const int* in_sizes, int n_in,
                              void* d_out, int out_size, void* d_ws, size_t ws_size,
                              hipStream_t stream)
{
    const float* x     = (const float*)d_in[0];
    const float* z     = (const float*)d_in[1];
    const int*   esrc  = (const int*)d_in[2];
    const int*   edst  = (const int*)d_in[3];
    const float* elem  = (const float*)d_in[4];
    const float* eattr = (const float*)d_in[5];
    const float* Wsi0  = (const float*)d_in[6];
    const float* Wsi1  = (const float*)d_in[7];
    const float* Wl10  = (const float*)d_in[8];
    const float* Wl11  = (const float*)d_in[9];
    const float* Wl20  = (const float*)d_in[10];
    const float* Wl21  = (const float*)d_in[11];
    const float* tpw   = (const float*)d_in[12];
    float* out = (float*)d_out;

    const int N = in_sizes[1] / ZDIM;      // 50000
    const int E = in_sizes[2];             // 500000

    float* xr    = (float*)d_ws;
    float* xlr   = xr    + (size_t)N * FEATD;
    float* s_buf = xlr   + (size_t)N * FEATD;
    float* aggr  = s_buf + (size_t)N * FEATD;

    hipMemsetAsync(aggr, 0, (size_t)N * FEATD * sizeof(float), stream);

    int g0 = (N * MULT + 255) / 256;
    hipLaunchKernelGGL(transform_x, dim3(g0), dim3(256), 0, stream, x, xr, N);

    int gn = (N + 255) / 256;
    hipLaunchKernelGGL(fctp_stageA, dim3(gn, 4), dim3(256), 0, stream,
                       xr, z, Wsi0, Wsi1, Wl10, Wl11, s_buf, xlr, N);

    int ge = (E + 63) / 64;
    hipLaunchKernelGGL(edge_kernel, dim3(ge), dim3(256), 0, stream,
                       esrc, edst, elem, eattr, tpw, xlr, aggr, E);

    hipLaunchKernelGGL(fctp_stageC, dim3(gn, 4), dim3(256), 0, stream,
                       aggr, z, Wl20, Wl21, s_buf, out, N);
}

// Round 2
// 2131.204 us; speedup vs baseline: 3.8231x; 3.8231x over previous
//
#include <hip/hip_runtime.h>

// Problem constants (from reference)
#define MULT 64
#define FEATD 256
#define ZDIM 10

#define INV640f 0.03952847075210474f   // 1/sqrt(640)
#define ISQ2f   0.7071067811865476f    // 1/sqrt(2)
#define ISQ3f   0.5773502691896258f    // 1/sqrt(3)

// ---------------------------------------------------------------------------
// K0: transform x (n,256 natural: [x0(64) | x1(64,3)]) -> xr (n,u,4) layout:
//     xr[n*256 + u*4 + 0] = x[n,u]            (x0)
//     xr[n*256 + u*4 + 1+k] = x[n, 64+3u+k]   (x1[u,k])
// ---------------------------------------------------------------------------
__global__ __launch_bounds__(256) void transform_x(
    const float* __restrict__ x, float* __restrict__ xr, int N)
{
    int idx = blockIdx.x * 256 + threadIdx.x;     // over N*64 (n,u) pairs
    if (idx >= N * MULT) return;
    int n = idx >> 6;
    int u = idx & 63;
    const float* row = x + (size_t)n * FEATD;
    float a = row[u];
    const float* x1p = row + MULT + u * 3;
    ((float4*)xr)[idx] = make_float4(a, x1p[0], x1p[1], x1p[2]);
}

// ---------------------------------------------------------------------------
// fctp inner loop (unchanged from round 1 — round 2 target for MFMA)
// ---------------------------------------------------------------------------
__device__ __forceinline__ void fctp_accum(
    const float4* __restrict__ xv4, const float* __restrict__ zr,
    const float* __restrict__ W0, const float* __restrict__ W1, int wb,
    float (&acc0)[16], float (&acc1)[16][3])
{
#pragma unroll
    for (int wi = 0; wi < 16; ++wi) {
        acc0[wi] = 0.f; acc1[wi][0] = 0.f; acc1[wi][1] = 0.f; acc1[wi][2] = 0.f;
    }
    for (int u = 0; u < MULT; ++u) {
        float4 xv = xv4[u];
#pragma unroll
        for (int v = 0; v < ZDIM; ++v) {
            float zv = zr[v];
            float b0 = xv.x * zv, b1 = xv.y * zv, b2 = xv.z * zv, b3 = xv.w * zv;
            const float* W0p = W0 + (u * ZDIM + v) * MULT + wb;
            const float* W1p = W1 + (u * ZDIM + v) * MULT + wb;
#pragma unroll
            for (int wi = 0; wi < 16; ++wi) {
                float w0v = W0p[wi];
                float w1v = W1p[wi];
                acc0[wi]    = fmaf(b0, w0v, acc0[wi]);
                acc1[wi][0] = fmaf(b1, w1v, acc1[wi][0]);
                acc1[wi][1] = fmaf(b2, w1v, acc1[wi][1]);
                acc1[wi][2] = fmaf(b3, w1v, acc1[wi][2]);
            }
        }
    }
}

// ---------------------------------------------------------------------------
// K1: stage A — s = fctp(x,z,W_si) (natural layout), xl = fctp(x,z,W_l1)
// ---------------------------------------------------------------------------
__global__ __launch_bounds__(256) void fctp_stageA(
    const float* __restrict__ xr, const float* __restrict__ z,
    const float* __restrict__ Wsi0, const float* __restrict__ Wsi1,
    const float* __restrict__ Wl10, const float* __restrict__ Wl11,
    float* __restrict__ s_out, float* __restrict__ xlr, int N)
{
    int n = blockIdx.x * 256 + threadIdx.x;
    if (n >= N) return;
    int wb = blockIdx.y * 16;

    float zr[ZDIM];
#pragma unroll
    for (int v = 0; v < ZDIM; ++v) zr[v] = z[n * ZDIM + v] * INV640f;

    const float4* xv4 = (const float4*)xr + (size_t)n * MULT;
    float acc0[16], acc1[16][3];

    // ---- fctp #1: s (natural layout) ----
    fctp_accum(xv4, zr, Wsi0, Wsi1, wb, acc0, acc1);
    {
        float* sp = s_out + (size_t)n * FEATD;
        float4* sp0 = (float4*)(sp + wb);
#pragma unroll
        for (int q = 0; q < 4; ++q)
            sp0[q] = make_float4(acc0[4*q], acc0[4*q+1], acc0[4*q+2], acc0[4*q+3]);
        float a1[48];
#pragma unroll
        for (int wi = 0; wi < 16; ++wi) {
            a1[3*wi] = acc1[wi][0]; a1[3*wi+1] = acc1[wi][1]; a1[3*wi+2] = acc1[wi][2];
        }
        float4* sp1 = (float4*)(sp + MULT + 3 * wb);
#pragma unroll
        for (int q = 0; q < 12; ++q)
            sp1[q] = make_float4(a1[4*q], a1[4*q+1], a1[4*q+2], a1[4*q+3]);
    }

    // ---- fctp #2: xl (xr layout, consumed by aggregate gather) ----
    fctp_accum(xv4, zr, Wl10, Wl11, wb, acc0, acc1);
    {
        float4* xp = (float4*)xlr + (size_t)n * MULT + wb;
#pragma unroll
        for (int wi = 0; wi < 16; ++wi)
            xp[wi] = make_float4(acc0[wi], acc1[wi][0], acc1[wi][1], acc1[wi][2]);
    }
}

// ---------------------------------------------------------------------------
// Counting sort of edges by dst: histogram -> 3-kernel exclusive scan ->
// scatter (perm). Replaces 128M float atomics with 1M int atomics.
// ---------------------------------------------------------------------------
__global__ __launch_bounds__(256) void hist_kernel(
    const int* __restrict__ edst, int* __restrict__ cnt, int E)
{
    int e = blockIdx.x * 256 + threadIdx.x;
    if (e >= E) return;
    atomicAdd(&cnt[edst[e]], 1);
}

// blocks of 1024: local inclusive scan, off[i+1] = local incl, bsum[b] = total
__global__ __launch_bounds__(1024) void scan_block(
    const int* __restrict__ cnt, int* __restrict__ off,
    int* __restrict__ bsum, int N)
{
    __shared__ int sh[1024];
    int tid = threadIdx.x;
    int i = blockIdx.x * 1024 + tid;
    int v = (i < N) ? cnt[i] : 0;
    sh[tid] = v;
    __syncthreads();
#pragma unroll
    for (int d = 1; d < 1024; d <<= 1) {
        int t = (tid >= d) ? sh[tid - d] : 0;
        __syncthreads();
        sh[tid] += t;
        __syncthreads();
    }
    if (i < N) off[i + 1] = sh[tid];
    if (tid == 1023) bsum[blockIdx.x] = sh[1023];
    if (i == 0) off[0] = 0;
}

// single wave: exclusive scan of block sums (nb <= 64, i.e. N <= 65536)
__global__ __launch_bounds__(64) void scan_sums(int* __restrict__ bsum, int nb)
{
    int tid = threadIdx.x;
    int v = (tid < nb) ? bsum[tid] : 0;
#pragma unroll
    for (int d = 1; d < 64; d <<= 1) {
        int t = __shfl_up(v, d, 64);
        if (tid >= d) v += t;
    }
    int ex = __shfl_up(v, 1, 64);
    if (tid == 0) ex = 0;
    if (tid < nb) bsum[tid] = ex;
}

__global__ __launch_bounds__(1024) void scan_add(
    int* __restrict__ off, const int* __restrict__ bsum, int N)
{
    int i = blockIdx.x * 1024 + threadIdx.x;
    if (i < N) off[i + 1] += bsum[blockIdx.x];
}

__global__ __launch_bounds__(256) void scatter_kernel(
    const int* __restrict__ edst, const int* __restrict__ off,
    int* __restrict__ cursor, int* __restrict__ perm, int E)
{
    int e = blockIdx.x * 256 + threadIdx.x;
    if (e >= E) return;
    int d = edst[e];
    int pos = off[d] + atomicAdd(&cursor[d], 1);
    perm[pos] = e;
}

// ---------------------------------------------------------------------------
// K2': aggregate. One wave per dst node; lane l owns u=l (xr-layout float4).
// Per edge in the node's bucket (edge id wave-uniform -> scalar loads):
//   w[c] = elem[e] . tpw[:,c] recomputed from register-resident tpw columns,
//   xlr[src] gathered coalesced (1KB/row), TP, accumulate in registers.
// Writes each agg row exactly once. No atomics, no LDS.
// ---------------------------------------------------------------------------
__global__ __launch_bounds__(256) void aggregate_kernel(
    const int* __restrict__ perm, const int* __restrict__ off,
    const int* __restrict__ esrc, const float* __restrict__ elem,
    const float* __restrict__ eattr, const float* __restrict__ tpw,
    const float* __restrict__ xlr, float* __restrict__ aggr, int N)
{
    int gid = blockIdx.x * 256 + threadIdx.x;
    int n = gid >> 6;            // one wave per node
    int l = gid & 63;            // lane = u index
    if (n >= N) return;

    // register-resident tp_weight columns for this lane:
    // tw[q*32+k] = tpw[k][q*64 + l]   (q: w1/w2/w3/w4 quarter)
    float tw[128];
#pragma unroll
    for (int k = 0; k < 32; ++k) {
#pragma unroll
        for (int q = 0; q < 4; ++q)
            tw[q * 32 + k] = tpw[k * 256 + q * 64 + l];
    }

    int s0 = off[n], s1 = off[n + 1];
    float4 acc = make_float4(0.f, 0.f, 0.f, 0.f);
    const float4* xlr4 = (const float4*)xlr;

    // prefetch edge 0's gather (the HBM-latency item)
    int e_nxt = 0;
    float4 xv_nxt = make_float4(0.f, 0.f, 0.f, 0.f);
    if (s0 < s1) {
        e_nxt = __builtin_amdgcn_readfirstlane(perm[s0]);
        int src = __builtin_amdgcn_readfirstlane(esrc[e_nxt]);
        xv_nxt = xlr4[(size_t)src * MULT + l];
    }

    for (int i = s0; i < s1; ++i) {
        int ecur = e_nxt;
        float4 xv = xv_nxt;
        if (i + 1 < s1) {
            e_nxt = __builtin_amdgcn_readfirstlane(perm[i + 1]);
            int src = __builtin_amdgcn_readfirstlane(esrc[e_nxt]);
            xv_nxt = xlr4[(size_t)src * MULT + l];
        }

        // elem row (wave-uniform address -> scalar/broadcast loads)
        const float* erow = elem + (size_t)ecur * 32;
        float w1 = 0.f, w2 = 0.f, w3 = 0.f, w4 = 0.f;
#pragma unroll
        for (int k4 = 0; k4 < 8; ++k4) {
            float4 ev = *(const float4*)(erow + k4 * 4);
            w1 = fmaf(ev.x, tw[0*32 + k4*4 + 0], w1);
            w2 = fmaf(ev.x, tw[1*32 + k4*4 + 0], w2);
            w3 = fmaf(ev.x, tw[2*32 + k4*4 + 0], w3);
            w4 = fmaf(ev.x, tw[3*32 + k4*4 + 0], w4);
            w1 = fmaf(ev.y, tw[0*32 + k4*4 + 1], w1);
            w2 = fmaf(ev.y, tw[1*32 + k4*4 + 1], w2);
            w3 = fmaf(ev.y, tw[2*32 + k4*4 + 1], w3);
            w4 = fmaf(ev.y, tw[3*32 + k4*4 + 1], w4);
            w1 = fmaf(ev.z, tw[0*32 + k4*4 + 2], w1);
            w2 = fmaf(ev.z, tw[1*32 + k4*4 + 2], w2);
            w3 = fmaf(ev.z, tw[2*32 + k4*4 + 2], w3);
            w4 = fmaf(ev.z, tw[3*32 + k4*4 + 2], w4);
            w1 = fmaf(ev.w, tw[0*32 + k4*4 + 3], w1);
            w2 = fmaf(ev.w, tw[1*32 + k4*4 + 3], w2);
            w3 = fmaf(ev.w, tw[2*32 + k4*4 + 3], w3);
            w4 = fmaf(ev.w, tw[3*32 + k4*4 + 3], w4);
        }

        float4 at = *(const float4*)(eattr + (size_t)ecur * 4);
        float sh0s = at.x * ISQ2f;
        float dot3 = xv.y * at.y + xv.z * at.z + xv.w * at.w;
        acc.x = fmaf(w1 * xv.x, sh0s, acc.x);
        acc.x = fmaf((ISQ2f * ISQ3f) * w4, dot3, acc.x);
        float w2x = ISQ2f * w2 * xv.x;
        acc.y = fmaf(w2x, at.y, acc.y);
        acc.z = fmaf(w2x, at.z, acc.z);
        acc.w = fmaf(w2x, at.w, acc.w);
        float w3s = w3 * sh0s;
        acc.y = fmaf(w3s, xv.y, acc.y);
        acc.z = fmaf(w3s, xv.z, acc.z);
        acc.w = fmaf(w3s, xv.w, acc.w);
    }

    ((float4*)aggr)[(size_t)n * MULT + l] = acc;
}

// ---------------------------------------------------------------------------
// K3: stage C — out = s + fctp(agg,z,W_l2)/10
// ---------------------------------------------------------------------------
__global__ __launch_bounds__(256) void fctp_stageC(
    const float* __restrict__ aggr, const float* __restrict__ z,
    const float* __restrict__ W0, const float* __restrict__ W1,
    const float* __restrict__ s_in, float* __restrict__ out, int N)
{
    int n = blockIdx.x * 256 + threadIdx.x;
    if (n >= N) return;
    int wb = blockIdx.y * 16;

    float zr[ZDIM];
#pragma unroll
    for (int v = 0; v < ZDIM; ++v) zr[v] = z[n * ZDIM + v] * (INV640f * 0.1f);

    const float4* xv4 = (const float4*)aggr + (size_t)n * MULT;
    float acc0[16], acc1[16][3];
    fctp_accum(xv4, zr, W0, W1, wb, acc0, acc1);

    const float* sp = s_in + (size_t)n * FEATD;
    float* op = out + (size_t)n * FEATD;

    const float4* s0 = (const float4*)(sp + wb);
    float4* o0 = (float4*)(op + wb);
#pragma unroll
    for (int q = 0; q < 4; ++q) {
        float4 sv = s0[q];
        o0[q] = make_float4(sv.x + acc0[4*q],   sv.y + acc0[4*q+1],
                            sv.z + acc0[4*q+2], sv.w + acc0[4*q+3]);
    }
    float a1[48];
#pragma unroll
    for (int wi = 0; wi < 16; ++wi) {
        a1[3*wi] = acc1[wi][0]; a1[3*wi+1] = acc1[wi][1]; a1[3*wi+2] = acc1[wi][2];
    }
    const float4* s1 = (const float4*)(sp + MULT + 3 * wb);
    float4* o1 = (float4*)(op + MULT + 3 * wb);
#pragma unroll
    for (int q = 0; q < 12; ++q) {
        float4 sv = s1[q];
        o1[q] = make_float4(sv.x + a1[4*q],   sv.y + a1[4*q+1],
                            sv.z + a1[4*q+2], sv.w + a1[4*q+3]);
    }
}

// ---------------------------------------------------------------------------
extern "C" void kernel_launch(void* const* d_in, const int* in_sizes, int n_in,
                              void* d_out, int out_size, void* d_ws, size_t ws_size,
                              hipStream_t stream)
{
    const float* x     = (const float*)d_in[0];
    const float* z     = (const float*)d_in[1];
    const int*   esrc  = (const int*)d_in[2];
    const int*   edst  = (const int*)d_in[3];
    const float* elem  = (const float*)d_in[4];
    const float* eattr = (const float*)d_in[5];
    const float* Wsi0  = (const float*)d_in[6];
    const float* Wsi1  = (const float*)d_in[7];
    const float* Wl10  = (const float*)d_in[8];
    const float* Wl11  = (const float*)d_in[9];
    const float* Wl20  = (const float*)d_in[10];
    const float* Wl21  = (const float*)d_in[11];
    const float* tpw   = (const float*)d_in[12];
    float* out = (float*)d_out;

    const int N = in_sizes[1] / ZDIM;      // 50000
    const int E = in_sizes[2];             // 500000

    float* xr    = (float*)d_ws;
    float* xlr   = xr    + (size_t)N * FEATD;
    float* s_buf = xlr   + (size_t)N * FEATD;
    float* aggr  = s_buf + (size_t)N * FEATD;

    // sort scratch aliases xr (dead after fctp_stageA). 3N+1+E + 64 ints
    // = ~2.6MB << N*256 floats = 51.2MB.
    int* cnt    = (int*)xr;
    int* cursor = cnt + N;
    int* off    = cursor + N;           // N+1 entries
    int* bsum   = off + (N + 1);        // up to 64 entries
    int* perm   = bsum + 64;            // E entries

    const int SCAN_B = 1024;
    int nb = (N + SCAN_B - 1) / SCAN_B; // 49 (<=64 required by scan_sums)

    int g0 = (N * MULT + 255) / 256;
    hipLaunchKernelGGL(transform_x, dim3(g0), dim3(256), 0, stream, x, xr, N);

    int gn = (N + 255) / 256;
    hipLaunchKernelGGL(fctp_stageA, dim3(gn, 4), dim3(256), 0, stream,
                       xr, z, Wsi0, Wsi1, Wl10, Wl11, s_buf, xlr, N);

    // xr is dead now -> build the dst-sorted edge permutation in its space
    hipMemsetAsync(cnt, 0, 2 * (size_t)N * sizeof(int), stream); // cnt+cursor
    int geh = (E + 255) / 256;
    hipLaunchKernelGGL(hist_kernel, dim3(geh), dim3(256), 0, stream,
                       edst, cnt, E);
    hipLaunchKernelGGL(scan_block, dim3(nb), dim3(SCAN_B), 0, stream,
                       cnt, off, bsum, N);
    hipLaunchKernelGGL(scan_sums, dim3(1), dim3(64), 0, stream, bsum, nb);
    hipLaunchKernelGGL(scan_add, dim3(nb), dim3(SCAN_B), 0, stream,
                       off, bsum, N);
    hipLaunchKernelGGL(scatter_kernel, dim3(geh), dim3(256), 0, stream,
                       edst, off, cursor, perm, E);

    int ga = (N * 64 + 255) / 256;
    hipLaunchKernelGGL(aggregate_kernel, dim3(ga), dim3(256), 0, stream,
                       perm, off, esrc, elem, eattr, tpw, xlr, aggr, N);

    hipLaunchKernelGGL(fctp_stageC, dim3(gn, 4), dim3(256), 0, stream,
                       aggr, z, Wl20, Wl21, s_buf, out, N);
}

// Round 3
// 838.366 us; speedup vs baseline: 9.7186x; 2.5421x over previous
//
#include <hip/hip_runtime.h>

// Problem constants (from reference)
#define MULT 64
#define FEATD 256
#define ZDIM 10

#define INV640f 0.03952847075210474f   // 1/sqrt(640)
#define ISQ2f   0.7071067811865476f    // 1/sqrt(2)
#define ISQ3f   0.5773502691896258f    // 1/sqrt(3)

typedef __bf16 bf16_t;
typedef bf16_t bf16x8_t __attribute__((ext_vector_type(8)));
typedef float  f32x4_t  __attribute__((ext_vector_type(4)));

// ---------------------------------------------------------------------------
// K0: transform x (n,256 natural: [x0(64) | x1(64,3)]) into bf16 GEMM rows:
//   Xs[n*64 + u]        = x0[n,u]        (N x 64)
//   Xv[(3n+k)*64 + u]   = x1[n,u,k]      (3N x 64)
// ---------------------------------------------------------------------------
__global__ __launch_bounds__(256) void transform_x2(
    const float* __restrict__ x, bf16_t* __restrict__ Xs,
    bf16_t* __restrict__ Xv, int N)
{
    int idx = blockIdx.x * 256 + threadIdx.x;     // over N*64 (n,u) pairs
    if (idx >= N * MULT) return;
    int n = idx >> 6;
    int u = idx & 63;
    const float* row = x + (size_t)n * FEATD;
    Xs[idx] = (bf16_t)row[u];
    const float* x1p = row + MULT + u * 3;
    Xv[((size_t)3 * n + 0) * MULT + u] = (bf16_t)x1p[0];
    Xv[((size_t)3 * n + 1) * MULT + u] = (bf16_t)x1p[1];
    Xv[((size_t)3 * n + 2) * MULT + u] = (bf16_t)x1p[2];
}

// ---------------------------------------------------------------------------
// MFMA fctp kernels. GEMM form: o[r,w] = sum_kk A[r,kk] * W[kk,w],
// kk = v*64+u (v=0..9, u=0..63, K=640 = 20 k-steps of 32),
// A[r,kk] = xrow[r,u] * z[node(r),v] formed in registers per k-step.
// W fragments (B operand) preloaded into registers per wave (16-col stripe).
// MFMA 16x16x32 bf16 layouts (m89/m91-verified):
//   A: [m=lane&15][k=(lane>>4)*8+j]   B: [k=(lane>>4)*8+j][n=lane&15]
//   C/D: col=lane&15, row=(lane>>4)*4+reg
// Blocks [0,128): scalar rows (N, weights *0); [128,512): vector (3N, *1).
// ---------------------------------------------------------------------------
__device__ __forceinline__ void preload_W(
    const float* __restrict__ W, int c0, int q, int mm, bf16x8_t (&B)[20])
{
    const int col = c0 + mm;
#pragma unroll
    for (int ks = 0; ks < 20; ++ks) {
        const int v = ks >> 1;
        const int ub = ((ks & 1) << 5) + (q << 3);
        const int base = v * 64 + col;
#pragma unroll
        for (int j = 0; j < 8; ++j)
            B[ks][j] = (bf16_t)W[(ub + j) * 640 + base];   // W[u][v][w]
    }
}

__global__ __launch_bounds__(256, 2) void fctp_stageA_mfma(
    const bf16_t* __restrict__ Xs, const bf16_t* __restrict__ Xv,
    const float* __restrict__ z,
    const float* __restrict__ Wsi0, const float* __restrict__ Wsi1,
    const float* __restrict__ Wl10, const float* __restrict__ Wl11,
    float* __restrict__ s_buf, float* __restrict__ xls,
    float* __restrict__ xlv, int N)
{
    const int lane = threadIdx.x & 63;
    const int wave = threadIdx.x >> 6;
    const int c0 = wave << 4;            // 16-col stripe per wave
    const int q = lane >> 4;
    const int mm = lane & 15;
    const bool sc = (int)blockIdx.x < 128;
    const float* WA = sc ? Wsi0 : Wsi1;
    const float* WB = sc ? Wl10 : Wl11;
    const bf16_t* Xsel = sc ? Xs : Xv;
    const int ntiles = sc ? (N >> 4) : ((3 * N) >> 4);
    const int worker = sc ? (int)blockIdx.x : ((int)blockIdx.x - 128);
    const int nworkers = sc ? 128 : 384;

    bf16x8_t BA[20], BB[20];
    preload_W(WA, c0, q, mm, BA);
    preload_W(WB, c0, q, mm, BB);

    for (int tile = worker; tile < ntiles; tile += nworkers) {
        const int r = (tile << 4) + mm;
        // this lane's 16 x-values: u in {q*8..q*8+7} and {32+q*8..32+q*8+7}
        bf16x8_t xlo = *(const bf16x8_t*)(Xsel + ((size_t)r << 6) + (q << 3));
        bf16x8_t xhi = *(const bf16x8_t*)(Xsel + ((size_t)r << 6) + 32 + (q << 3));
        float xf[16];
#pragma unroll
        for (int j = 0; j < 8; ++j) { xf[j] = (float)xlo[j]; xf[8 + j] = (float)xhi[j]; }
        const unsigned node = sc ? (unsigned)r : ((unsigned)r / 3u);
        float zr[ZDIM];
#pragma unroll
        for (int v = 0; v < ZDIM; ++v) zr[v] = z[(size_t)node * ZDIM + v] * INV640f;

        f32x4_t accA = {0.f, 0.f, 0.f, 0.f}, accB = {0.f, 0.f, 0.f, 0.f};
#pragma unroll
        for (int ks = 0; ks < 20; ++ks) {
            const float zv = zr[ks >> 1];
            const int xo = (ks & 1) << 3;
            bf16x8_t af;
#pragma unroll
            for (int j = 0; j < 8; ++j) af[j] = (bf16_t)(zv * xf[xo + j]);
            accA = __builtin_amdgcn_mfma_f32_16x16x32_bf16(af, BA[ks], accA, 0, 0, 0);
            accB = __builtin_amdgcn_mfma_f32_16x16x32_bf16(af, BB[ks], accB, 0, 0, 0);
        }

        const int w = c0 + mm;
        const int rb = (tile << 4) + (q << 2);
#pragma unroll
        for (int reg = 0; reg < 4; ++reg) {
            const int ro = rb + reg;
            if (sc) {
                s_buf[(size_t)ro * FEATD + w] = accA[reg];
                xls[((size_t)ro << 6) + w] = accB[reg];
            } else {
                const unsigned nn = (unsigned)ro / 3u;
                const int k = ro - 3 * (int)nn;
                s_buf[(size_t)nn * FEATD + MULT + w * 3 + k] = accA[reg];
                xlv[((size_t)ro << 6) + w] = accB[reg];
            }
        }
    }
}

__global__ __launch_bounds__(256, 2) void fctp_stageC_mfma(
    const float* __restrict__ aggs, const float* __restrict__ aggv,
    const float* __restrict__ z,
    const float* __restrict__ Wl20, const float* __restrict__ Wl21,
    const float* __restrict__ s_buf, float* __restrict__ out, int N)
{
    const int lane = threadIdx.x & 63;
    const int wave = threadIdx.x >> 6;
    const int c0 = wave << 4;
    const int q = lane >> 4;
    const int mm = lane & 15;
    const bool sc = (int)blockIdx.x < 128;
    const float* W = sc ? Wl20 : Wl21;
    const float* Asel = sc ? aggs : aggv;
    const int ntiles = sc ? (N >> 4) : ((3 * N) >> 4);
    const int worker = sc ? (int)blockIdx.x : ((int)blockIdx.x - 128);
    const int nworkers = sc ? 128 : 384;

    bf16x8_t B[20];
    preload_W(W, c0, q, mm, B);

    for (int tile = worker; tile < ntiles; tile += nworkers) {
        const int r = (tile << 4) + mm;
        const float* ap = Asel + ((size_t)r << 6) + (q << 3);
        float4 l0 = *(const float4*)(ap);
        float4 l1 = *(const float4*)(ap + 4);
        float4 h0 = *(const float4*)(ap + 32);
        float4 h1 = *(const float4*)(ap + 36);
        float xf[16] = {l0.x, l0.y, l0.z, l0.w, l1.x, l1.y, l1.z, l1.w,
                        h0.x, h0.y, h0.z, h0.w, h1.x, h1.y, h1.z, h1.w};
        const unsigned node = sc ? (unsigned)r : ((unsigned)r / 3u);
        float zr[ZDIM];
#pragma unroll
        for (int v = 0; v < ZDIM; ++v)
            zr[v] = z[(size_t)node * ZDIM + v] * (INV640f * 0.1f);

        f32x4_t acc = {0.f, 0.f, 0.f, 0.f};
#pragma unroll
        for (int ks = 0; ks < 20; ++ks) {
            const float zv = zr[ks >> 1];
            const int xo = (ks & 1) << 3;
            bf16x8_t af;
#pragma unroll
            for (int j = 0; j < 8; ++j) af[j] = (bf16_t)(zv * xf[xo + j]);
            acc = __builtin_amdgcn_mfma_f32_16x16x32_bf16(af, B[ks], acc, 0, 0, 0);
        }

        const int w = c0 + mm;
        const int rb = (tile << 4) + (q << 2);
#pragma unroll
        for (int reg = 0; reg < 4; ++reg) {
            const int ro = rb + reg;
            size_t idx;
            if (sc) {
                idx = (size_t)ro * FEATD + w;
            } else {
                const unsigned nn = (unsigned)ro / 3u;
                const int k = ro - 3 * (int)nn;
                idx = (size_t)nn * FEATD + MULT + w * 3 + k;
            }
            out[idx] = s_buf[idx] + acc[reg];
        }
    }
}

// ---------------------------------------------------------------------------
// Counting sort of edges by dst (unchanged from round 2)
// ---------------------------------------------------------------------------
__global__ __launch_bounds__(256) void hist_kernel(
    const int* __restrict__ edst, int* __restrict__ cnt, int E)
{
    int e = blockIdx.x * 256 + threadIdx.x;
    if (e >= E) return;
    atomicAdd(&cnt[edst[e]], 1);
}

__global__ __launch_bounds__(1024) void scan_block(
    const int* __restrict__ cnt, int* __restrict__ off,
    int* __restrict__ bsum, int N)
{
    __shared__ int sh[1024];
    int tid = threadIdx.x;
    int i = blockIdx.x * 1024 + tid;
    int v = (i < N) ? cnt[i] : 0;
    sh[tid] = v;
    __syncthreads();
#pragma unroll
    for (int d = 1; d < 1024; d <<= 1) {
        int t = (tid >= d) ? sh[tid - d] : 0;
        __syncthreads();
        sh[tid] += t;
        __syncthreads();
    }
    if (i < N) off[i + 1] = sh[tid];
    if (tid == 1023) bsum[blockIdx.x] = sh[1023];
    if (i == 0) off[0] = 0;
}

__global__ __launch_bounds__(64) void scan_sums(int* __restrict__ bsum, int nb)
{
    int tid = threadIdx.x;
    int v = (tid < nb) ? bsum[tid] : 0;
#pragma unroll
    for (int d = 1; d < 64; d <<= 1) {
        int t = __shfl_up(v, d, 64);
        if (tid >= d) v += t;
    }
    int ex = __shfl_up(v, 1, 64);
    if (tid == 0) ex = 0;
    if (tid < nb) bsum[tid] = ex;
}

__global__ __launch_bounds__(1024) void scan_add(
    int* __restrict__ off, const int* __restrict__ bsum, int N)
{
    int i = blockIdx.x * 1024 + threadIdx.x;
    if (i < N) off[i + 1] += bsum[blockIdx.x];
}

__global__ __launch_bounds__(256) void scatter_kernel(
    const int* __restrict__ edst, const int* __restrict__ off,
    int* __restrict__ cursor, int* __restrict__ perm, int E)
{
    int e = blockIdx.x * 256 + threadIdx.x;
    if (e >= E) return;
    int d = edst[e];
    int pos = off[d] + atomicAdd(&cursor[d], 1);
    perm[pos] = e;
}

// ---------------------------------------------------------------------------
// K2': aggregate. One wave per dst node; lane l owns u=l. Gathers from split
// xls/xlv (coalesced 256B rows), writes aggs/aggv exactly once. No atomics.
// ---------------------------------------------------------------------------
__global__ __launch_bounds__(256) void aggregate_kernel(
    const int* __restrict__ perm, const int* __restrict__ off,
    const int* __restrict__ esrc, const float* __restrict__ elem,
    const float* __restrict__ eattr, const float* __restrict__ tpw,
    const float* __restrict__ xls, const float* __restrict__ xlv,
    float* __restrict__ aggs, float* __restrict__ aggv, int N)
{
    int gid = blockIdx.x * 256 + threadIdx.x;
    int n = gid >> 6;            // one wave per node
    int l = gid & 63;            // lane = u index
    if (n >= N) return;

    // register-resident tp_weight columns for this lane:
    // tw[qq*32+k] = tpw[k][qq*64 + l]   (qq: w1/w2/w3/w4 quarter)
    float tw[128];
#pragma unroll
    for (int k = 0; k < 32; ++k) {
#pragma unroll
        for (int qq = 0; qq < 4; ++qq)
            tw[qq * 32 + k] = tpw[k * 256 + qq * 64 + l];
    }

    int s0 = off[n], s1 = off[n + 1];
    float4 acc = make_float4(0.f, 0.f, 0.f, 0.f);

    // prefetch edge 0's gather (the HBM-latency item)
    int e_nxt = 0;
    float4 xv_nxt = make_float4(0.f, 0.f, 0.f, 0.f);
    if (s0 < s1) {
        e_nxt = __builtin_amdgcn_readfirstlane(perm[s0]);
        int src = __builtin_amdgcn_readfirstlane(esrc[e_nxt]);
        xv_nxt.x = xls[((size_t)src << 6) + l];
        xv_nxt.y = xlv[((size_t)(3 * src + 0) << 6) + l];
        xv_nxt.z = xlv[((size_t)(3 * src + 1) << 6) + l];
        xv_nxt.w = xlv[((size_t)(3 * src + 2) << 6) + l];
    }

    for (int i = s0; i < s1; ++i) {
        int ecur = e_nxt;
        float4 xv = xv_nxt;
        if (i + 1 < s1) {
            e_nxt = __builtin_amdgcn_readfirstlane(perm[i + 1]);
            int src = __builtin_amdgcn_readfirstlane(esrc[e_nxt]);
            xv_nxt.x = xls[((size_t)src << 6) + l];
            xv_nxt.y = xlv[((size_t)(3 * src + 0) << 6) + l];
            xv_nxt.z = xlv[((size_t)(3 * src + 1) << 6) + l];
            xv_nxt.w = xlv[((size_t)(3 * src + 2) << 6) + l];
        }

        // elem row (wave-uniform address -> scalar/broadcast loads)
        const float* erow = elem + (size_t)ecur * 32;
        float w1 = 0.f, w2 = 0.f, w3 = 0.f, w4 = 0.f;
#pragma unroll
        for (int k4 = 0; k4 < 8; ++k4) {
            float4 ev = *(const float4*)(erow + k4 * 4);
            w1 = fmaf(ev.x, tw[0*32 + k4*4 + 0], w1);
            w2 = fmaf(ev.x, tw[1*32 + k4*4 + 0], w2);
            w3 = fmaf(ev.x, tw[2*32 + k4*4 + 0], w3);
            w4 = fmaf(ev.x, tw[3*32 + k4*4 + 0], w4);
            w1 = fmaf(ev.y, tw[0*32 + k4*4 + 1], w1);
            w2 = fmaf(ev.y, tw[1*32 + k4*4 + 1], w2);
            w3 = fmaf(ev.y, tw[2*32 + k4*4 + 1], w3);
            w4 = fmaf(ev.y, tw[3*32 + k4*4 + 1], w4);
            w1 = fmaf(ev.z, tw[0*32 + k4*4 + 2], w1);
            w2 = fmaf(ev.z, tw[1*32 + k4*4 + 2], w2);
            w3 = fmaf(ev.z, tw[2*32 + k4*4 + 2], w3);
            w4 = fmaf(ev.z, tw[3*32 + k4*4 + 2], w4);
            w1 = fmaf(ev.w, tw[0*32 + k4*4 + 3], w1);
            w2 = fmaf(ev.w, tw[1*32 + k4*4 + 3], w2);
            w3 = fmaf(ev.w, tw[2*32 + k4*4 + 3], w3);
            w4 = fmaf(ev.w, tw[3*32 + k4*4 + 3], w4);
        }

        float4 at = *(const float4*)(eattr + (size_t)ecur * 4);
        float sh0s = at.x * ISQ2f;
        float dot3 = xv.y * at.y + xv.z * at.z + xv.w * at.w;
        acc.x = fmaf(w1 * xv.x, sh0s, acc.x);
        acc.x = fmaf((ISQ2f * ISQ3f) * w4, dot3, acc.x);
        float w2x = ISQ2f * w2 * xv.x;
        acc.y = fmaf(w2x, at.y, acc.y);
        acc.z = fmaf(w2x, at.z, acc.z);
        acc.w = fmaf(w2x, at.w, acc.w);
        float w3s = w3 * sh0s;
        acc.y = fmaf(w3s, xv.y, acc.y);
        acc.z = fmaf(w3s, xv.z, acc.z);
        acc.w = fmaf(w3s, xv.w, acc.w);
    }

    aggs[((size_t)n << 6) + l] = acc.x;
    aggv[((size_t)(3 * n + 0) << 6) + l] = acc.y;
    aggv[((size_t)(3 * n + 1) << 6) + l] = acc.z;
    aggv[((size_t)(3 * n + 2) << 6) + l] = acc.w;
}

// ---------------------------------------------------------------------------
extern "C" void kernel_launch(void* const* d_in, const int* in_sizes, int n_in,
                              void* d_out, int out_size, void* d_ws, size_t ws_size,
                              hipStream_t stream)
{
    const float* x     = (const float*)d_in[0];
    const float* z     = (const float*)d_in[1];
    const int*   esrc  = (const int*)d_in[2];
    const int*   edst  = (const int*)d_in[3];
    const float* elem  = (const float*)d_in[4];
    const float* eattr = (const float*)d_in[5];
    const float* Wsi0  = (const float*)d_in[6];
    const float* Wsi1  = (const float*)d_in[7];
    const float* Wl10  = (const float*)d_in[8];
    const float* Wl11  = (const float*)d_in[9];
    const float* Wl20  = (const float*)d_in[10];
    const float* Wl21  = (const float*)d_in[11];
    const float* tpw   = (const float*)d_in[12];
    float* out = (float*)d_out;

    const int N = in_sizes[1] / ZDIM;      // 50000
    const int E = in_sizes[2];             // 500000

    // workspace carve-up (~182 MB)
    float* xls   = (float*)d_ws;                       // N*64
    float* xlv   = xls   + (size_t)N * 64;             // 3N*64
    float* aggs  = xlv   + (size_t)3 * N * 64;         // N*64
    float* aggv  = aggs  + (size_t)N * 64;             // 3N*64
    float* s_buf = aggv  + (size_t)3 * N * 64;         // N*256
    bf16_t* Xs   = (bf16_t*)(s_buf + (size_t)N * FEATD);   // N*64 bf16
    bf16_t* Xv   = Xs + (size_t)N * 64;                    // 3N*64 bf16
    int* cnt     = (int*)(Xv + (size_t)3 * N * 64);
    int* cursor  = cnt + N;
    int* off     = cursor + N;           // N+1 entries
    int* bsum    = off + (N + 1);        // up to 64 entries
    int* perm    = bsum + 64;            // E entries

    const int SCAN_B = 1024;
    int nb = (N + SCAN_B - 1) / SCAN_B;  // 49 (<=64 required by scan_sums)

    hipMemsetAsync(cnt, 0, 2 * (size_t)N * sizeof(int), stream); // cnt+cursor

    int g0 = (N * MULT + 255) / 256;
    hipLaunchKernelGGL(transform_x2, dim3(g0), dim3(256), 0, stream, x, Xs, Xv, N);

    hipLaunchKernelGGL(fctp_stageA_mfma, dim3(512), dim3(256), 0, stream,
                       Xs, Xv, z, Wsi0, Wsi1, Wl10, Wl11, s_buf, xls, xlv, N);

    int geh = (E + 255) / 256;
    hipLaunchKernelGGL(hist_kernel, dim3(geh), dim3(256), 0, stream,
                       edst, cnt, E);
    hipLaunchKernelGGL(scan_block, dim3(nb), dim3(SCAN_B), 0, stream,
                       cnt, off, bsum, N);
    hipLaunchKernelGGL(scan_sums, dim3(1), dim3(64), 0, stream, bsum, nb);
    hipLaunchKernelGGL(scan_add, dim3(nb), dim3(SCAN_B), 0, stream,
                       off, bsum, N);
    hipLaunchKernelGGL(scatter_kernel, dim3(geh), dim3(256), 0, stream,
                       edst, off, cursor, perm, E);

    int ga = (N * 64 + 255) / 256;
    hipLaunchKernelGGL(aggregate_kernel, dim3(ga), dim3(256), 0, stream,
                       perm, off, esrc, elem, eattr, tpw, xls, xlv,
                       aggs, aggv, N);

    hipLaunchKernelGGL(fctp_stageC_mfma, dim3(512), dim3(256), 0, stream,
                       aggs, aggv, z, Wl20, Wl21, s_buf, out, N);
}

// Round 4
// 688.893 us; speedup vs baseline: 11.8273x; 1.2170x over previous
//
#include <hip/hip_runtime.h>

// Problem constants (from reference)
#define MULT 64
#define FEATD 256
#define ZDIM 10

#define INV640f 0.03952847075210474f   // 1/sqrt(640)
#define ISQ2f   0.7071067811865476f    // 1/sqrt(2)
#define ISQ3f   0.5773502691896258f    // 1/sqrt(3)

typedef __bf16 bf16_t;
typedef bf16_t bf16x8_t __attribute__((ext_vector_type(8)));
typedef float  f32x4_t  __attribute__((ext_vector_type(4)));

// ---------------------------------------------------------------------------
// K0: transform x (n,256 natural: [x0(64) | x1(64,3)]) into bf16 GEMM rows:
//   Xs[n*64 + u]        = x0[n,u]        (N x 64)
//   Xv[(3n+k)*64 + u]   = x1[n,u,k]      (3N x 64)
// ---------------------------------------------------------------------------
__global__ __launch_bounds__(256) void transform_x2(
    const float* __restrict__ x, bf16_t* __restrict__ Xs,
    bf16_t* __restrict__ Xv, int N)
{
    int idx = blockIdx.x * 256 + threadIdx.x;     // over N*64 (n,u) pairs
    if (idx >= N * MULT) return;
    int n = idx >> 6;
    int u = idx & 63;
    const float* row = x + (size_t)n * FEATD;
    Xs[idx] = (bf16_t)row[u];
    const float* x1p = row + MULT + u * 3;
    Xv[((size_t)3 * n + 0) * MULT + u] = (bf16_t)x1p[0];
    Xv[((size_t)3 * n + 1) * MULT + u] = (bf16_t)x1p[1];
    Xv[((size_t)3 * n + 2) * MULT + u] = (bf16_t)x1p[2];
}

// ---------------------------------------------------------------------------
// MFMA fctp kernels (unchanged from round 3 — verified correct/fast).
// ---------------------------------------------------------------------------
__device__ __forceinline__ void preload_W(
    const float* __restrict__ W, int c0, int q, int mm, bf16x8_t (&B)[20])
{
    const int col = c0 + mm;
#pragma unroll
    for (int ks = 0; ks < 20; ++ks) {
        const int v = ks >> 1;
        const int ub = ((ks & 1) << 5) + (q << 3);
        const int base = v * 64 + col;
#pragma unroll
        for (int j = 0; j < 8; ++j)
            B[ks][j] = (bf16_t)W[(ub + j) * 640 + base];   // W[u][v][w]
    }
}

__global__ __launch_bounds__(256, 2) void fctp_stageA_mfma(
    const bf16_t* __restrict__ Xs, const bf16_t* __restrict__ Xv,
    const float* __restrict__ z,
    const float* __restrict__ Wsi0, const float* __restrict__ Wsi1,
    const float* __restrict__ Wl10, const float* __restrict__ Wl11,
    float* __restrict__ s_buf, float* __restrict__ xls,
    float* __restrict__ xlv, int N)
{
    const int lane = threadIdx.x & 63;
    const int wave = threadIdx.x >> 6;
    const int c0 = wave << 4;            // 16-col stripe per wave
    const int q = lane >> 4;
    const int mm = lane & 15;
    const bool sc = (int)blockIdx.x < 128;
    const float* WA = sc ? Wsi0 : Wsi1;
    const float* WB = sc ? Wl10 : Wl11;
    const bf16_t* Xsel = sc ? Xs : Xv;
    const int ntiles = sc ? (N >> 4) : ((3 * N) >> 4);
    const int worker = sc ? (int)blockIdx.x : ((int)blockIdx.x - 128);
    const int nworkers = sc ? 128 : 384;

    bf16x8_t BA[20], BB[20];
    preload_W(WA, c0, q, mm, BA);
    preload_W(WB, c0, q, mm, BB);

    for (int tile = worker; tile < ntiles; tile += nworkers) {
        const int r = (tile << 4) + mm;
        bf16x8_t xlo = *(const bf16x8_t*)(Xsel + ((size_t)r << 6) + (q << 3));
        bf16x8_t xhi = *(const bf16x8_t*)(Xsel + ((size_t)r << 6) + 32 + (q << 3));
        float xf[16];
#pragma unroll
        for (int j = 0; j < 8; ++j) { xf[j] = (float)xlo[j]; xf[8 + j] = (float)xhi[j]; }
        const unsigned node = sc ? (unsigned)r : ((unsigned)r / 3u);
        float zr[ZDIM];
#pragma unroll
        for (int v = 0; v < ZDIM; ++v) zr[v] = z[(size_t)node * ZDIM + v] * INV640f;

        f32x4_t accA = {0.f, 0.f, 0.f, 0.f}, accB = {0.f, 0.f, 0.f, 0.f};
#pragma unroll
        for (int ks = 0; ks < 20; ++ks) {
            const float zv = zr[ks >> 1];
            const int xo = (ks & 1) << 3;
            bf16x8_t af;
#pragma unroll
            for (int j = 0; j < 8; ++j) af[j] = (bf16_t)(zv * xf[xo + j]);
            accA = __builtin_amdgcn_mfma_f32_16x16x32_bf16(af, BA[ks], accA, 0, 0, 0);
            accB = __builtin_amdgcn_mfma_f32_16x16x32_bf16(af, BB[ks], accB, 0, 0, 0);
        }

        const int w = c0 + mm;
        const int rb = (tile << 4) + (q << 2);
#pragma unroll
        for (int reg = 0; reg < 4; ++reg) {
            const int ro = rb + reg;
            if (sc) {
                s_buf[(size_t)ro * FEATD + w] = accA[reg];
                xls[((size_t)ro << 6) + w] = accB[reg];
            } else {
                const unsigned nn = (unsigned)ro / 3u;
                const int k = ro - 3 * (int)nn;
                s_buf[(size_t)nn * FEATD + MULT + w * 3 + k] = accA[reg];
                xlv[((size_t)ro << 6) + w] = accB[reg];
            }
        }
    }
}

__global__ __launch_bounds__(256, 2) void fctp_stageC_mfma(
    const float* __restrict__ aggs, const float* __restrict__ aggv,
    const float* __restrict__ z,
    const float* __restrict__ Wl20, const float* __restrict__ Wl21,
    const float* __restrict__ s_buf, float* __restrict__ out, int N)
{
    const int lane = threadIdx.x & 63;
    const int wave = threadIdx.x >> 6;
    const int c0 = wave << 4;
    const int q = lane >> 4;
    const int mm = lane & 15;
    const bool sc = (int)blockIdx.x < 128;
    const float* W = sc ? Wl20 : Wl21;
    const float* Asel = sc ? aggs : aggv;
    const int ntiles = sc ? (N >> 4) : ((3 * N) >> 4);
    const int worker = sc ? (int)blockIdx.x : ((int)blockIdx.x - 128);
    const int nworkers = sc ? 128 : 384;

    bf16x8_t B[20];
    preload_W(W, c0, q, mm, B);

    for (int tile = worker; tile < ntiles; tile += nworkers) {
        const int r = (tile << 4) + mm;
        const float* ap = Asel + ((size_t)r << 6) + (q << 3);
        float4 l0 = *(const float4*)(ap);
        float4 l1 = *(const float4*)(ap + 4);
        float4 h0 = *(const float4*)(ap + 32);
        float4 h1 = *(const float4*)(ap + 36);
        float xf[16] = {l0.x, l0.y, l0.z, l0.w, l1.x, l1.y, l1.z, l1.w,
                        h0.x, h0.y, h0.z, h0.w, h1.x, h1.y, h1.z, h1.w};
        const unsigned node = sc ? (unsigned)r : ((unsigned)r / 3u);
        float zr[ZDIM];
#pragma unroll
        for (int v = 0; v < ZDIM; ++v)
            zr[v] = z[(size_t)node * ZDIM + v] * (INV640f * 0.1f);

        f32x4_t acc = {0.f, 0.f, 0.f, 0.f};
#pragma unroll
        for (int ks = 0; ks < 20; ++ks) {
            const float zv = zr[ks >> 1];
            const int xo = (ks & 1) << 3;
            bf16x8_t af;
#pragma unroll
            for (int j = 0; j < 8; ++j) af[j] = (bf16_t)(zv * xf[xo + j]);
            acc = __builtin_amdgcn_mfma_f32_16x16x32_bf16(af, B[ks], acc, 0, 0, 0);
        }

        const int w = c0 + mm;
        const int rb = (tile << 4) + (q << 2);
#pragma unroll
        for (int reg = 0; reg < 4; ++reg) {
            const int ro = rb + reg;
            size_t idx;
            if (sc) {
                idx = (size_t)ro * FEATD + w;
            } else {
                const unsigned nn = (unsigned)ro / 3u;
                const int k = ro - 3 * (int)nn;
                idx = (size_t)nn * FEATD + MULT + w * 3 + k;
            }
            out[idx] = s_buf[idx] + acc[reg];
        }
    }
}

// ---------------------------------------------------------------------------
// Counting sort of edges by dst. scatter now also emits sperm (permuted src)
// and eattr_p (permuted edge_attr) so the aggregate loop reads sequentially.
// ---------------------------------------------------------------------------
__global__ __launch_bounds__(256) void hist_kernel(
    const int* __restrict__ edst, int* __restrict__ cnt, int E)
{
    int e = blockIdx.x * 256 + threadIdx.x;
    if (e >= E) return;
    atomicAdd(&cnt[edst[e]], 1);
}

__global__ __launch_bounds__(1024) void scan_block(
    const int* __restrict__ cnt, int* __restrict__ off,
    int* __restrict__ bsum, int N)
{
    __shared__ int sh[1024];
    int tid = threadIdx.x;
    int i = blockIdx.x * 1024 + tid;
    int v = (i < N) ? cnt[i] : 0;
    sh[tid] = v;
    __syncthreads();
#pragma unroll
    for (int d = 1; d < 1024; d <<= 1) {
        int t = (tid >= d) ? sh[tid - d] : 0;
        __syncthreads();
        sh[tid] += t;
        __syncthreads();
    }
    if (i < N) off[i + 1] = sh[tid];
    if (tid == 1023) bsum[blockIdx.x] = sh[1023];
    if (i == 0) off[0] = 0;
}

__global__ __launch_bounds__(64) void scan_sums(int* __restrict__ bsum, int nb)
{
    int tid = threadIdx.x;
    int v = (tid < nb) ? bsum[tid] : 0;
#pragma unroll
    for (int d = 1; d < 64; d <<= 1) {
        int t = __shfl_up(v, d, 64);
        if (tid >= d) v += t;
    }
    int ex = __shfl_up(v, 1, 64);
    if (tid == 0) ex = 0;
    if (tid < nb) bsum[tid] = ex;
}

__global__ __launch_bounds__(1024) void scan_add(
    int* __restrict__ off, const int* __restrict__ bsum, int N)
{
    int i = blockIdx.x * 1024 + threadIdx.x;
    if (i < N) off[i + 1] += bsum[blockIdx.x];
}

__global__ __launch_bounds__(256) void scatter_kernel(
    const int* __restrict__ edst, const int* __restrict__ esrc,
    const float* __restrict__ eattr, const int* __restrict__ off,
    int* __restrict__ cursor, int* __restrict__ perm,
    int* __restrict__ sperm, float* __restrict__ eattr_p, int E)
{
    int e = blockIdx.x * 256 + threadIdx.x;
    if (e >= E) return;
    int d = edst[e];
    int pos = off[d] + atomicAdd(&cursor[d], 1);
    perm[pos] = e;
    sperm[pos] = esrc[e];
    float4 at = *(const float4*)(eattr + (size_t)e * 4);
    *(float4*)(eattr_p + (size_t)pos * 4) = at;
}

// permute elem rows into dst-sorted order (coalesced write, gathered read)
__global__ __launch_bounds__(256) void permute_elem(
    const int* __restrict__ perm, const float* __restrict__ elem,
    float* __restrict__ elem_p, int E)
{
    int idx = blockIdx.x * 256 + threadIdx.x;   // over E*32
    if (idx >= E * 32) return;
    int i = idx >> 5, d = idx & 31;
    elem_p[idx] = elem[((size_t)perm[i] << 5) + d];
}

// ---------------------------------------------------------------------------
// K2'': aggregate, k-split. 2 waves per node: wave covers 32 u's x 2 k-halves
// (lane = kh*32 + ul, u = uh*32+ul). Per-lane tp_weight residency = 64 VGPRs
// (was 128 -> spilled). Partial-k w's are linear in the TP, so partial accs
// are combined once per node via shfl_xor(32). Sequential streams for
// sperm/elem_p/eattr_p; depth-2 prefetch on the xls/xlv gather.
// ---------------------------------------------------------------------------
__device__ __forceinline__ void agg_edge(
    float xs, float v0, float v1, float v2, int i, int kh,
    const float* __restrict__ elem_p, const float* __restrict__ eattr_p,
    const float (&tw0)[16], const float (&tw1)[16],
    const float (&tw2)[16], const float (&tw3)[16],
    float& accx, float& accy, float& accz, float& accw)
{
    const float* er = elem_p + ((size_t)i << 5) + (kh << 4);
    float4 e0 = *(const float4*)(er);
    float4 e1 = *(const float4*)(er + 4);
    float4 e2 = *(const float4*)(er + 8);
    float4 e3 = *(const float4*)(er + 12);
    float ev[16] = {e0.x, e0.y, e0.z, e0.w, e1.x, e1.y, e1.z, e1.w,
                    e2.x, e2.y, e2.z, e2.w, e3.x, e3.y, e3.z, e3.w};
    float w1p = 0.f, w2p = 0.f, w3p = 0.f, w4p = 0.f;
#pragma unroll
    for (int j = 0; j < 16; ++j) {
        w1p = fmaf(ev[j], tw0[j], w1p);
        w2p = fmaf(ev[j], tw1[j], w2p);
        w3p = fmaf(ev[j], tw2[j], w3p);
        w4p = fmaf(ev[j], tw3[j], w4p);
    }
    float4 at = *(const float4*)(eattr_p + ((size_t)i << 2));
    float sh0s = at.x * ISQ2f;
    float dot3 = v0 * at.y + v1 * at.z + v2 * at.w;
    accx = fmaf(w1p * xs, sh0s, accx);
    accx = fmaf((ISQ2f * ISQ3f) * w4p, dot3, accx);
    float w2x = ISQ2f * w2p * xs;
    accy = fmaf(w2x, at.y, accy);
    accz = fmaf(w2x, at.z, accz);
    accw = fmaf(w2x, at.w, accw);
    float w3s = w3p * sh0s;
    accy = fmaf(w3s, v0, accy);
    accz = fmaf(w3s, v1, accz);
    accw = fmaf(w3s, v2, accw);
}

__global__ __launch_bounds__(256, 4) void aggregate3(
    const int* __restrict__ off, const int* __restrict__ sperm,
    const float* __restrict__ elem_p, const float* __restrict__ eattr_p,
    const float* __restrict__ tpw,
    const float* __restrict__ xls, const float* __restrict__ xlv,
    float* __restrict__ aggs, float* __restrict__ aggv, int N)
{
    int wv = (blockIdx.x * 256 + threadIdx.x) >> 6;
    int n = wv >> 1;
    if (n >= N) return;
    int uh = wv & 1;
    int l = threadIdx.x & 63;
    int ul = l & 31, kh = l >> 5;
    int u = (uh << 5) + ul;

    // per-lane tp_weight columns: 4 qq x 16 k-half = 64 registers
    float tw0[16], tw1[16], tw2[16], tw3[16];
#pragma unroll
    for (int j = 0; j < 16; ++j) {
        const float* tp = tpw + ((kh << 4) + j) * 256 + u;
        tw0[j] = tp[0];
        tw1[j] = tp[64];
        tw2[j] = tp[128];
        tw3[j] = tp[192];
    }

    int s0 = __builtin_amdgcn_readfirstlane(off[n]);
    int s1 = __builtin_amdgcn_readfirstlane(off[n + 1]);

    float accx = 0.f, accy = 0.f, accz = 0.f, accw = 0.f;

    if (s0 < s1) {
        const int last = s1 - 1;
        // prefetch slot A (edge s0) and slot B (edge s0+1, clamped)
        int sa = __builtin_amdgcn_readfirstlane(sperm[s0]);
        float a_xs = xls[((size_t)sa << 6) + u];
        float a_v0 = xlv[((size_t)(3 * sa + 0) << 6) + u];
        float a_v1 = xlv[((size_t)(3 * sa + 1) << 6) + u];
        float a_v2 = xlv[((size_t)(3 * sa + 2) << 6) + u];
        int ib = (s0 + 1 <= last) ? s0 + 1 : last;
        int sb = __builtin_amdgcn_readfirstlane(sperm[ib]);
        float b_xs = xls[((size_t)sb << 6) + u];
        float b_v0 = xlv[((size_t)(3 * sb + 0) << 6) + u];
        float b_v1 = xlv[((size_t)(3 * sb + 1) << 6) + u];
        float b_v2 = xlv[((size_t)(3 * sb + 2) << 6) + u];

        int i = s0;
        while (true) {
            // process slot A (edge i), refill A with edge i+2
            agg_edge(a_xs, a_v0, a_v1, a_v2, i, kh, elem_p, eattr_p,
                     tw0, tw1, tw2, tw3, accx, accy, accz, accw);
            {
                int inx = (i + 2 <= last) ? i + 2 : last;
                int sn = __builtin_amdgcn_readfirstlane(sperm[inx]);
                a_xs = xls[((size_t)sn << 6) + u];
                a_v0 = xlv[((size_t)(3 * sn + 0) << 6) + u];
                a_v1 = xlv[((size_t)(3 * sn + 1) << 6) + u];
                a_v2 = xlv[((size_t)(3 * sn + 2) << 6) + u];
            }
            if (++i >= s1) break;
            // process slot B (edge i), refill B with edge i+2
            agg_edge(b_xs, b_v0, b_v1, b_v2, i, kh, elem_p, eattr_p,
                     tw0, tw1, tw2, tw3, accx, accy, accz, accw);
            {
                int inx = (i + 2 <= last) ? i + 2 : last;
                int sn = __builtin_amdgcn_readfirstlane(sperm[inx]);
                b_xs = xls[((size_t)sn << 6) + u];
                b_v0 = xlv[((size_t)(3 * sn + 0) << 6) + u];
                b_v1 = xlv[((size_t)(3 * sn + 1) << 6) + u];
                b_v2 = xlv[((size_t)(3 * sn + 2) << 6) + u];
            }
            if (++i >= s1) break;
        }
    }

    // combine the two k-halves (TP is linear in w -> linear in acc)
    accx += __shfl_xor(accx, 32, 64);
    accy += __shfl_xor(accy, 32, 64);
    accz += __shfl_xor(accz, 32, 64);
    accw += __shfl_xor(accw, 32, 64);

    if (kh == 0) {
        aggs[((size_t)n << 6) + u] = accx;
        aggv[((size_t)(3 * n + 0) << 6) + u] = accy;
        aggv[((size_t)(3 * n + 1) << 6) + u] = accz;
        aggv[((size_t)(3 * n + 2) << 6) + u] = accw;
    }
}

// ---------------------------------------------------------------------------
extern "C" void kernel_launch(void* const* d_in, const int* in_sizes, int n_in,
                              void* d_out, int out_size, void* d_ws, size_t ws_size,
                              hipStream_t stream)
{
    const float* x     = (const float*)d_in[0];
    const float* z     = (const float*)d_in[1];
    const int*   esrc  = (const int*)d_in[2];
    const int*   edst  = (const int*)d_in[3];
    const float* elem  = (const float*)d_in[4];
    const float* eattr = (const float*)d_in[5];
    const float* Wsi0  = (const float*)d_in[6];
    const float* Wsi1  = (const float*)d_in[7];
    const float* Wl10  = (const float*)d_in[8];
    const float* Wl11  = (const float*)d_in[9];
    const float* Wl20  = (const float*)d_in[10];
    const float* Wl21  = (const float*)d_in[11];
    const float* tpw   = (const float*)d_in[12];
    float* out = (float*)d_out;

    const int N = in_sizes[1] / ZDIM;      // 50000
    const int E = in_sizes[2];             // 500000

    // workspace carve-up (~230 MB):
    float* xls   = (float*)d_ws;                       // N*64
    float* xlv   = xls   + (size_t)N * 64;             // 3N*64
    float* aggs  = xlv   + (size_t)3 * N * 64;         // N*64
    float* aggv  = aggs  + (size_t)N * 64;             // 3N*64
    float* s_buf = aggv  + (size_t)3 * N * 64;         // N*256
    // region R: union of {Xs,Xv} (dead after stageA) and {elem_p,eattr_p,sperm}
    char*  R     = (char*)(s_buf + (size_t)N * FEATD);
    bf16_t* Xs   = (bf16_t*)R;                         // N*64 bf16
    bf16_t* Xv   = Xs + (size_t)N * 64;                // 3N*64 bf16
    float* elem_p  = (float*)R;                        // E*32 f32
    float* eattr_p = elem_p + (size_t)E * 32;          // E*4  f32
    int*   sperm   = (int*)(eattr_p + (size_t)E * 4);  // E    i32
    size_t R_bytes_a = (size_t)4 * N * 64 * sizeof(bf16_t);     // Xs+Xv
    size_t R_bytes_b = ((size_t)E * 36) * 4 + (size_t)E * 4;    // elem_p+eattr_p+sperm
    size_t R_bytes = R_bytes_a > R_bytes_b ? R_bytes_a : R_bytes_b;
    int* cnt     = (int*)(R + R_bytes);
    int* cursor  = cnt + N;
    int* off     = cursor + N;           // N+1 entries
    int* bsum    = off + (N + 1);        // up to 64 entries
    int* perm    = bsum + 64;            // E entries

    const int SCAN_B = 1024;
    int nb = (N + SCAN_B - 1) / SCAN_B;  // 49 (<=64 required by scan_sums)

    hipMemsetAsync(cnt, 0, 2 * (size_t)N * sizeof(int), stream); // cnt+cursor

    int g0 = (N * MULT + 255) / 256;
    hipLaunchKernelGGL(transform_x2, dim3(g0), dim3(256), 0, stream, x, Xs, Xv, N);

    hipLaunchKernelGGL(fctp_stageA_mfma, dim3(512), dim3(256), 0, stream,
                       Xs, Xv, z, Wsi0, Wsi1, Wl10, Wl11, s_buf, xls, xlv, N);

    int geh = (E + 255) / 256;
    hipLaunchKernelGGL(hist_kernel, dim3(geh), dim3(256), 0, stream,
                       edst, cnt, E);
    hipLaunchKernelGGL(scan_block, dim3(nb), dim3(SCAN_B), 0, stream,
                       cnt, off, bsum, N);
    hipLaunchKernelGGL(scan_sums, dim3(1), dim3(64), 0, stream, bsum, nb);
    hipLaunchKernelGGL(scan_add, dim3(nb), dim3(SCAN_B), 0, stream,
                       off, bsum, N);
    hipLaunchKernelGGL(scatter_kernel, dim3(geh), dim3(256), 0, stream,
                       edst, esrc, eattr, off, cursor, perm, sperm, eattr_p, E);
    int gpe = (E * 32 + 255) / 256;
    hipLaunchKernelGGL(permute_elem, dim3(gpe), dim3(256), 0, stream,
                       perm, elem, elem_p, E);

    int ga = (2 * N * 64 + 255) / 256;   // 2 waves per node
    hipLaunchKernelGGL(aggregate3, dim3(ga), dim3(256), 0, stream,
                       off, sperm, elem_p, eattr_p, tpw, xls, xlv,
                       aggs, aggv, N);

    hipLaunchKernelGGL(fctp_stageC_mfma, dim3(512), dim3(256), 0, stream,
                       aggs, aggv, z, Wl20, Wl21, s_buf, out, N);
}

// Round 5
// 620.219 us; speedup vs baseline: 13.1369x; 1.1107x over previous
//
#include <hip/hip_runtime.h>

// Problem constants (from reference)
#define MULT 64
#define FEATD 256
#define ZDIM 10

#define INV640f 0.03952847075210474f   // 1/sqrt(640)
#define ISQ2f   0.7071067811865476f    // 1/sqrt(2)
#define ISQ3f   0.5773502691896258f    // 1/sqrt(3)

typedef _Float16 f16_t;
typedef f16_t f16x8_t __attribute__((ext_vector_type(8)));
typedef f16_t f16x4_t __attribute__((ext_vector_type(4)));
typedef float f32x4_t __attribute__((ext_vector_type(4)));

// ---------------------------------------------------------------------------
// K0: transform x (n,256 natural: [x0(64) | x1(64,3)]) into f16 GEMM rows:
//   Xs[n*64 + u]        = x0[n,u]        (N x 64)
//   Xv[(3n+k)*64 + u]   = x1[n,u,k]      (3N x 64)
// ---------------------------------------------------------------------------
__global__ __launch_bounds__(256) void transform_x2(
    const float* __restrict__ x, f16_t* __restrict__ Xs,
    f16_t* __restrict__ Xv, int N)
{
    int idx = blockIdx.x * 256 + threadIdx.x;     // over N*64 (n,u) pairs
    if (idx >= N * MULT) return;
    int n = idx >> 6;
    int u = idx & 63;
    const float* row = x + (size_t)n * FEATD;
    Xs[idx] = (f16_t)row[u];
    const float* x1p = row + MULT + u * 3;
    Xv[((size_t)3 * n + 0) * MULT + u] = (f16_t)x1p[0];
    Xv[((size_t)3 * n + 1) * MULT + u] = (f16_t)x1p[1];
    Xv[((size_t)3 * n + 2) * MULT + u] = (f16_t)x1p[2];
}

// ---------------------------------------------------------------------------
// MFMA fctp kernels (f16). GEMM form: o[r,w] = sum_kk A[r,kk]*W[kk,w],
// kk = v*64+u, A[r,kk] = xrow[r,u]*z[node(r),v] formed in registers.
// 16x16x32 layouts: A [m=lane&15][k=q*8+j], B [k=q*8+j][n=lane&15],
// C/D col=lane&15, row=q*4+reg  (m89/m91-verified).
// ---------------------------------------------------------------------------
__device__ __forceinline__ void preload_W(
    const float* __restrict__ W, int c0, int q, int mm, f16x8_t (&B)[20])
{
    const int col = c0 + mm;
#pragma unroll
    for (int ks = 0; ks < 20; ++ks) {
        const int v = ks >> 1;
        const int ub = ((ks & 1) << 5) + (q << 3);
        const int base = v * 64 + col;
#pragma unroll
        for (int j = 0; j < 8; ++j)
            B[ks][j] = (f16_t)W[(ub + j) * 640 + base];   // W[u][v][w]
    }
}

__global__ __launch_bounds__(256, 2) void fctp_stageA_mfma(
    const f16_t* __restrict__ Xs, const f16_t* __restrict__ Xv,
    const float* __restrict__ z,
    const float* __restrict__ Wsi0, const float* __restrict__ Wsi1,
    const float* __restrict__ Wl10, const float* __restrict__ Wl11,
    float* __restrict__ out, f16_t* __restrict__ xls,
    f16_t* __restrict__ xlv, int N)
{
    const int lane = threadIdx.x & 63;
    const int wave = threadIdx.x >> 6;
    const int c0 = wave << 4;            // 16-col stripe per wave
    const int q = lane >> 4;
    const int mm = lane & 15;
    const bool sc = (int)blockIdx.x < 128;
    const float* WA = sc ? Wsi0 : Wsi1;
    const float* WB = sc ? Wl10 : Wl11;
    const f16_t* Xsel = sc ? Xs : Xv;
    const int ntiles = sc ? (N >> 4) : ((3 * N) >> 4);
    const int worker = sc ? (int)blockIdx.x : ((int)blockIdx.x - 128);
    const int nworkers = sc ? 128 : 384;

    f16x8_t BA[20], BB[20];
    preload_W(WA, c0, q, mm, BA);
    preload_W(WB, c0, q, mm, BB);

    for (int tile = worker; tile < ntiles; tile += nworkers) {
        const int r = (tile << 4) + mm;
        f16x8_t xlo = *(const f16x8_t*)(Xsel + ((size_t)r << 6) + (q << 3));
        f16x8_t xhi = *(const f16x8_t*)(Xsel + ((size_t)r << 6) + 32 + (q << 3));
        float xf[16];
#pragma unroll
        for (int j = 0; j < 8; ++j) { xf[j] = (float)xlo[j]; xf[8 + j] = (float)xhi[j]; }
        const unsigned node = sc ? (unsigned)r : ((unsigned)r / 3u);
        float zr[ZDIM];
#pragma unroll
        for (int v = 0; v < ZDIM; ++v) zr[v] = z[(size_t)node * ZDIM + v] * INV640f;

        f32x4_t accA = {0.f, 0.f, 0.f, 0.f}, accB = {0.f, 0.f, 0.f, 0.f};
#pragma unroll
        for (int ks = 0; ks < 20; ++ks) {
            const float zv = zr[ks >> 1];
            const int xo = (ks & 1) << 3;
            f16x8_t af;
#pragma unroll
            for (int j = 0; j < 8; ++j) af[j] = (f16_t)(zv * xf[xo + j]);
            accA = __builtin_amdgcn_mfma_f32_16x16x32_f16(af, BA[ks], accA, 0, 0, 0);
            accB = __builtin_amdgcn_mfma_f32_16x16x32_f16(af, BB[ks], accB, 0, 0, 0);
        }

        const int w = c0 + mm;
        const int rb = (tile << 4) + (q << 2);
#pragma unroll
        for (int reg = 0; reg < 4; ++reg) {
            const int ro = rb + reg;
            if (sc) {
                out[(size_t)ro * FEATD + w] = accA[reg];          // s, scalar part
                xls[((size_t)ro << 6) + w] = (f16_t)accB[reg];
            } else {
                const unsigned nn = (unsigned)ro / 3u;
                const int k = ro - 3 * (int)nn;
                out[(size_t)nn * FEATD + MULT + w * 3 + k] = accA[reg];  // s, vec part
                xlv[((size_t)ro << 6) + w] = (f16_t)accB[reg];
            }
        }
    }
}

__global__ __launch_bounds__(256, 2) void fctp_stageC_mfma(
    const float* __restrict__ aggs, const float* __restrict__ aggv,
    const float* __restrict__ z,
    const float* __restrict__ Wl20, const float* __restrict__ Wl21,
    float* __restrict__ out, int N)
{
    const int lane = threadIdx.x & 63;
    const int wave = threadIdx.x >> 6;
    const int c0 = wave << 4;
    const int q = lane >> 4;
    const int mm = lane & 15;
    const bool sc = (int)blockIdx.x < 128;
    const float* W = sc ? Wl20 : Wl21;
    const float* Asel = sc ? aggs : aggv;
    const int ntiles = sc ? (N >> 4) : ((3 * N) >> 4);
    const int worker = sc ? (int)blockIdx.x : ((int)blockIdx.x - 128);
    const int nworkers = sc ? 128 : 384;

    f16x8_t B[20];
    preload_W(W, c0, q, mm, B);

    for (int tile = worker; tile < ntiles; tile += nworkers) {
        const int r = (tile << 4) + mm;
        const float* ap = Asel + ((size_t)r << 6) + (q << 3);
        float4 l0 = *(const float4*)(ap);
        float4 l1 = *(const float4*)(ap + 4);
        float4 h0 = *(const float4*)(ap + 32);
        float4 h1 = *(const float4*)(ap + 36);
        float xf[16] = {l0.x, l0.y, l0.z, l0.w, l1.x, l1.y, l1.z, l1.w,
                        h0.x, h0.y, h0.z, h0.w, h1.x, h1.y, h1.z, h1.w};
        const unsigned node = sc ? (unsigned)r : ((unsigned)r / 3u);
        float zr[ZDIM];
#pragma unroll
        for (int v = 0; v < ZDIM; ++v)
            zr[v] = z[(size_t)node * ZDIM + v] * (INV640f * 0.1f);

        f32x4_t acc = {0.f, 0.f, 0.f, 0.f};
#pragma unroll
        for (int ks = 0; ks < 20; ++ks) {
            const float zv = zr[ks >> 1];
            const int xo = (ks & 1) << 3;
            f16x8_t af;
#pragma unroll
            for (int j = 0; j < 8; ++j) af[j] = (f16_t)(zv * xf[xo + j]);
            acc = __builtin_amdgcn_mfma_f32_16x16x32_f16(af, B[ks], acc, 0, 0, 0);
        }

        const int w = c0 + mm;
        const int rb = (tile << 4) + (q << 2);
#pragma unroll
        for (int reg = 0; reg < 4; ++reg) {
            const int ro = rb + reg;
            size_t idx;
            if (sc) {
                idx = (size_t)ro * FEATD + w;
            } else {
                const unsigned nn = (unsigned)ro / 3u;
                const int k = ro - 3 * (int)nn;
                idx = (size_t)nn * FEATD + MULT + w * 3 + k;
            }
            out[idx] = out[idx] + acc[reg];   // s was staged in out by stageA
        }
    }
}

// ---------------------------------------------------------------------------
// Counting sort of edges by dst (unchanged). scatter emits perm, sperm
// (permuted src) and eattr_p (permuted edge_attr).
// ---------------------------------------------------------------------------
__global__ __launch_bounds__(256) void hist_kernel(
    const int* __restrict__ edst, int* __restrict__ cnt, int E)
{
    int e = blockIdx.x * 256 + threadIdx.x;
    if (e >= E) return;
    atomicAdd(&cnt[edst[e]], 1);
}

__global__ __launch_bounds__(1024) void scan_block(
    const int* __restrict__ cnt, int* __restrict__ off,
    int* __restrict__ bsum, int N)
{
    __shared__ int sh[1024];
    int tid = threadIdx.x;
    int i = blockIdx.x * 1024 + tid;
    int v = (i < N) ? cnt[i] : 0;
    sh[tid] = v;
    __syncthreads();
#pragma unroll
    for (int d = 1; d < 1024; d <<= 1) {
        int t = (tid >= d) ? sh[tid - d] : 0;
        __syncthreads();
        sh[tid] += t;
        __syncthreads();
    }
    if (i < N) off[i + 1] = sh[tid];
    if (tid == 1023) bsum[blockIdx.x] = sh[1023];
    if (i == 0) off[0] = 0;
}

__global__ __launch_bounds__(64) void scan_sums(int* __restrict__ bsum, int nb)
{
    int tid = threadIdx.x;
    int v = (tid < nb) ? bsum[tid] : 0;
#pragma unroll
    for (int d = 1; d < 64; d <<= 1) {
        int t = __shfl_up(v, d, 64);
        if (tid >= d) v += t;
    }
    int ex = __shfl_up(v, 1, 64);
    if (tid == 0) ex = 0;
    if (tid < nb) bsum[tid] = ex;
}

__global__ __launch_bounds__(1024) void scan_add(
    int* __restrict__ off, const int* __restrict__ bsum, int N)
{
    int i = blockIdx.x * 1024 + threadIdx.x;
    if (i < N) off[i + 1] += bsum[blockIdx.x];
}

__global__ __launch_bounds__(256) void scatter_kernel(
    const int* __restrict__ edst, const int* __restrict__ esrc,
    const float* __restrict__ eattr, const int* __restrict__ off,
    int* __restrict__ cursor, int* __restrict__ perm,
    int* __restrict__ sperm, float* __restrict__ eattr_p, int E)
{
    int e = blockIdx.x * 256 + threadIdx.x;
    if (e >= E) return;
    int d = edst[e];
    int pos = off[d] + atomicAdd(&cursor[d], 1);
    perm[pos] = e;
    sperm[pos] = esrc[e];
    float4 at = *(const float4*)(eattr + (size_t)e * 4);
    *(float4*)(eattr_p + (size_t)pos * 4) = at;
}

// ---------------------------------------------------------------------------
// wgemm: w = elem[perm[pos]] @ tpw via MFMA, for positions [lo, lo+16*ntiles).
// One wave per 16-edge tile, 16 MFMAs cover all 256 w-cols. ISQ2/ISQ3 scales
// folded into the f16 output: wbuf[(pos-lo)*64 + u][0..3] = w1',w2',w3',w4'.
// Replaces permute_elem AND the 64-FMA/lane w-loop in aggregate.
// ---------------------------------------------------------------------------
__global__ __launch_bounds__(256, 2) void wgemm_kernel(
    const int* __restrict__ perm, const float* __restrict__ elem,
    const float* __restrict__ tpw, f16_t* __restrict__ wbuf,
    int lo, int ntiles)
{
    int tt = blockIdx.x * 4 + (threadIdx.x >> 6);
    if (tt >= ntiles) return;
    const int lane = threadIdx.x & 63;
    const int mm = lane & 15, q = lane >> 4;

    // B-frags: stripe s covers cols s*16 + mm, k = q*8+j
    f16x8_t B[16];
#pragma unroll
    for (int s = 0; s < 16; ++s)
#pragma unroll
        for (int j = 0; j < 8; ++j)
            B[s][j] = (f16_t)tpw[(q * 8 + j) * 256 + s * 16 + mm];

    // A-frag: edge row mm of tile, k = q*8..q*8+7 (elem row gathered via perm)
    int p = lo + tt * 16 + mm;
    int e = perm[p];
    const float* er = elem + ((size_t)e << 5) + q * 8;
    float4 ea = *(const float4*)er;
    float4 eb = *(const float4*)(er + 4);
    f16x8_t A;
    A[0] = (f16_t)ea.x; A[1] = (f16_t)ea.y; A[2] = (f16_t)ea.z; A[3] = (f16_t)ea.w;
    A[4] = (f16_t)eb.x; A[5] = (f16_t)eb.y; A[6] = (f16_t)eb.z; A[7] = (f16_t)eb.w;

    f32x4_t D[16];
#pragma unroll
    for (int s = 0; s < 16; ++s) {
        f32x4_t zer = {0.f, 0.f, 0.f, 0.f};
        D[s] = __builtin_amdgcn_mfma_f32_16x16x32_f16(A, B[s], zer, 0, 0, 0);
    }

    // store: D col = s*16+mm -> qq = s>>2, u = (s&3)*16+mm; row = q*4+reg
#pragma unroll
    for (int reg = 0; reg < 4; ++reg) {
        const int row = q * 4 + reg;
        const size_t base = ((size_t)(tt * 16 + row)) << 6;   // row in wbuf
#pragma unroll
        for (int t = 0; t < 4; ++t) {
            const int u = t * 16 + mm;
            f16x4_t wq;
            wq[0] = (f16_t)(D[0 * 4 + t][reg] * ISQ2f);
            wq[1] = (f16_t)(D[1 * 4 + t][reg] * ISQ2f);
            wq[2] = (f16_t)(D[2 * 4 + t][reg] * ISQ2f);
            wq[3] = (f16_t)(D[3 * 4 + t][reg] * (ISQ2f * ISQ3f));
            *(f16x4_t*)(wbuf + ((base + u) << 2)) = wq;
        }
    }
}

// ---------------------------------------------------------------------------
// aggregate5: 1 wave per node, chunked over edge positions [lo, hi).
// Per edge: 8B w-load (coalesced), f16 gathers of xl[src], ~14-FMA TP,
// += into aggs/aggv (zero-initialized; same wave owns node in both chunks).
// ---------------------------------------------------------------------------
__device__ __forceinline__ void agg_edge5(
    float xs, float v0, float v1, float v2, int i, int lo,
    const f16_t* __restrict__ wbuf, const float* __restrict__ eattr_p, int u,
    float& accx, float& accy, float& accz, float& accw)
{
    f16x4_t wq = *(const f16x4_t*)(wbuf + ((((size_t)(i - lo)) << 6) + u) * 4);
    float w1 = (float)wq[0], w2 = (float)wq[1], w3 = (float)wq[2], w4 = (float)wq[3];
    float4 at = *(const float4*)(eattr_p + ((size_t)i << 2));
    float dot3 = v0 * at.y + v1 * at.z + v2 * at.w;
    accx = fmaf(w1 * xs, at.x, accx);
    accx = fmaf(w4, dot3, accx);
    float w2x = w2 * xs;
    accy = fmaf(w2x, at.y, accy);
    accz = fmaf(w2x, at.z, accz);
    accw = fmaf(w2x, at.w, accw);
    float w3s = w3 * at.x;
    accy = fmaf(w3s, v0, accy);
    accz = fmaf(w3s, v1, accz);
    accw = fmaf(w3s, v2, accw);
}

__global__ __launch_bounds__(256, 8) void aggregate5(
    const int* __restrict__ off, const int* __restrict__ sperm,
    const f16_t* __restrict__ wbuf, const float* __restrict__ eattr_p,
    const f16_t* __restrict__ xls, const f16_t* __restrict__ xlv,
    float* __restrict__ aggs, float* __restrict__ aggv,
    int N, int lo, int hi)
{
    int n = (blockIdx.x * 256 + threadIdx.x) >> 6;      // one wave per node
    if (n >= N) return;
    int u = threadIdx.x & 63;

    int s0 = __builtin_amdgcn_readfirstlane(off[n]);
    int s1 = __builtin_amdgcn_readfirstlane(off[n + 1]);
    int cs0 = s0 > lo ? s0 : lo;
    int cs1 = s1 < hi ? s1 : hi;
    if (cs0 >= cs1) return;

    float accx = 0.f, accy = 0.f, accz = 0.f, accw = 0.f;
    const int last = cs1 - 1;

    // depth-2 prefetch slots for the xl gather (the HBM-latency item)
    int sa = __builtin_amdgcn_readfirstlane(sperm[cs0]);
    float a_xs = (float)xls[((size_t)sa << 6) + u];
    float a_v0 = (float)xlv[((size_t)(3 * sa + 0) << 6) + u];
    float a_v1 = (float)xlv[((size_t)(3 * sa + 1) << 6) + u];
    float a_v2 = (float)xlv[((size_t)(3 * sa + 2) << 6) + u];
    int ib = (cs0 + 1 <= last) ? cs0 + 1 : last;
    int sb = __builtin_amdgcn_readfirstlane(sperm[ib]);
    float b_xs = (float)xls[((size_t)sb << 6) + u];
    float b_v0 = (float)xlv[((size_t)(3 * sb + 0) << 6) + u];
    float b_v1 = (float)xlv[((size_t)(3 * sb + 1) << 6) + u];
    float b_v2 = (float)xlv[((size_t)(3 * sb + 2) << 6) + u];

    int i = cs0;
    while (true) {
        agg_edge5(a_xs, a_v0, a_v1, a_v2, i, lo, wbuf, eattr_p, u,
                  accx, accy, accz, accw);
        {
            int inx = (i + 2 <= last) ? i + 2 : last;
            int sn = __builtin_amdgcn_readfirstlane(sperm[inx]);
            a_xs = (float)xls[((size_t)sn << 6) + u];
            a_v0 = (float)xlv[((size_t)(3 * sn + 0) << 6) + u];
            a_v1 = (float)xlv[((size_t)(3 * sn + 1) << 6) + u];
            a_v2 = (float)xlv[((size_t)(3 * sn + 2) << 6) + u];
        }
        if (++i > last) break;
        agg_edge5(b_xs, b_v0, b_v1, b_v2, i, lo, wbuf, eattr_p, u,
                  accx, accy, accz, accw);
        {
            int inx = (i + 2 <= last) ? i + 2 : last;
            int sn = __builtin_amdgcn_readfirstlane(sperm[inx]);
            b_xs = (float)xls[((size_t)sn << 6) + u];
            b_v0 = (float)xlv[((size_t)(3 * sn + 0) << 6) + u];
            b_v1 = (float)xlv[((size_t)(3 * sn + 1) << 6) + u];
            b_v2 = (float)xlv[((size_t)(3 * sn + 2) << 6) + u];
        }
        if (++i > last) break;
    }

    aggs[((size_t)n << 6) + u] += accx;
    aggv[((size_t)(3 * n + 0) << 6) + u] += accy;
    aggv[((size_t)(3 * n + 1) << 6) + u] += accz;
    aggv[((size_t)(3 * n + 2) << 6) + u] += accw;
}

// ---------------------------------------------------------------------------
extern "C" void kernel_launch(void* const* d_in, const int* in_sizes, int n_in,
                              void* d_out, int out_size, void* d_ws, size_t ws_size,
                              hipStream_t stream)
{
    const float* x     = (const float*)d_in[0];
    const float* z     = (const float*)d_in[1];
    const int*   esrc  = (const int*)d_in[2];
    const int*   edst  = (const int*)d_in[3];
    const float* elem  = (const float*)d_in[4];
    const float* eattr = (const float*)d_in[5];
    const float* Wsi0  = (const float*)d_in[6];
    const float* Wsi1  = (const float*)d_in[7];
    const float* Wl10  = (const float*)d_in[8];
    const float* Wl11  = (const float*)d_in[9];
    const float* Wl20  = (const float*)d_in[10];
    const float* Wl21  = (const float*)d_in[11];
    const float* tpw   = (const float*)d_in[12];
    float* out = (float*)d_out;

    const int N = in_sizes[1] / ZDIM;      // 50000
    const int E = in_sizes[2];             // 500000
    const int Ehalf = E / 2;               // 250000 (divisible by 16)

    // workspace carve-up (~218 MB, under the ~230 MB proven in rounds 3/4):
    f16_t* xls  = (f16_t*)d_ws;                          // N*64   f16
    f16_t* xlv  = xls + (size_t)N * 64;                  // 3N*64  f16
    float* aggs = (float*)(xlv + (size_t)3 * N * 64);    // N*64   f32
    float* aggv = aggs + (size_t)N * 64;                 // 3N*64  f32
    // region R: union of {Xs,Xv} (dead after stageA) and wbuf (per-chunk w)
    char*  R    = (char*)(aggv + (size_t)3 * N * 64);
    f16_t* Xs   = (f16_t*)R;                             // N*64   f16
    f16_t* Xv   = Xs + (size_t)N * 64;                   // 3N*64  f16
    f16_t* wbuf = (f16_t*)R;                             // Ehalf*256 f16 = 128 MB
    size_t Rbytes = (size_t)Ehalf * 256 * sizeof(f16_t);
    float* eattr_p = (float*)(R + Rbytes);               // E*4 f32
    int*   sperm   = (int*)(eattr_p + (size_t)E * 4);    // E
    int*   perm    = sperm + E;                          // E
    int*   cnt     = perm + E;                           // N
    int*   cursor  = cnt + N;                            // N
    int*   off     = cursor + N;                         // N+1
    int*   bsum    = off + (N + 1);                      // 64

    const int SCAN_B = 1024;
    int nb = (N + SCAN_B - 1) / SCAN_B;  // 49 (<=64 required by scan_sums)

    hipMemsetAsync(cnt, 0, 2 * (size_t)N * sizeof(int), stream);       // cnt+cursor
    hipMemsetAsync(aggs, 0, (size_t)4 * N * 64 * sizeof(float), stream); // aggs+aggv

    int g0 = (N * MULT + 255) / 256;
    hipLaunchKernelGGL(transform_x2, dim3(g0), dim3(256), 0, stream, x, Xs, Xv, N);

    hipLaunchKernelGGL(fctp_stageA_mfma, dim3(512), dim3(256), 0, stream,
                       Xs, Xv, z, Wsi0, Wsi1, Wl10, Wl11, out, xls, xlv, N);

    int geh = (E + 255) / 256;
    hipLaunchKernelGGL(hist_kernel, dim3(geh), dim3(256), 0, stream,
                       edst, cnt, E);
    hipLaunchKernelGGL(scan_block, dim3(nb), dim3(SCAN_B), 0, stream,
                       cnt, off, bsum, N);
    hipLaunchKernelGGL(scan_sums, dim3(1), dim3(64), 0, stream, bsum, nb);
    hipLaunchKernelGGL(scan_add, dim3(nb), dim3(SCAN_B), 0, stream,
                       off, bsum, N);
    hipLaunchKernelGGL(scatter_kernel, dim3(geh), dim3(256), 0, stream,
                       edst, esrc, eattr, off, cursor, perm, sperm, eattr_p, E);

    // two node-aligned edge chunks: wgemm (w via MFMA) -> aggregate (+=)
    int wt = Ehalf / 16;                       // 15625 tiles per chunk
    int gw = (wt + 3) / 4;
    int ga = (N * 64 + 255) / 256;
    for (int c = 0; c < 2; ++c) {
        int lo = c * Ehalf, hi = lo + Ehalf;
        hipLaunchKernelGGL(wgemm_kernel, dim3(gw), dim3(256), 0, stream,
                           perm, elem, tpw, wbuf, lo, wt);
        hipLaunchKernelGGL(aggregate5, dim3(ga), dim3(256), 0, stream,
                           off, sperm, wbuf, eattr_p, xls, xlv,
                           aggs, aggv, N, lo, hi);
    }

    hipLaunchKernelGGL(fctp_stageC_mfma, dim3(512), dim3(256), 0, stream,
                       aggs, aggv, z, Wl20, Wl21, out, N);
}